// Round 5
// baseline (235.500 us; speedup 1.0000x reference)
//
#include <hip/hip_runtime.h>

typedef unsigned short u16;
typedef __attribute__((ext_vector_type(8))) short short8;
typedef __attribute__((ext_vector_type(4))) float f32x4;

__device__ __forceinline__ u16 f2b(float f) {
  union { float f; unsigned u; } v; v.f = f;
  unsigned u = v.u;
  return (u16)((u + 0x7FFFu + ((u >> 16) & 1u)) >> 16);
}
__device__ __forceinline__ u16 f2b_trunc(float f) {
  union { float f; unsigned u; } v; v.f = f;
  return (u16)(v.u >> 16);
}
// async global->LDS, 16B per lane; LDS base must be wave-uniform (lane scatters +lane*16B)
__device__ __forceinline__ void glds16(const u16* g, u16* l) {
  __builtin_amdgcn_global_load_lds((const __attribute__((address_space(1))) void*)g,
                                   (__attribute__((address_space(3))) void*)l, 16, 0, 0);
}

// ---------------- fused prep: 5x fp32->bf16 convert + interleaved cos/sin table ------
__global__ __launch_bounds__(256) void prep_k(const float* __restrict__ x,
                                              const float* __restrict__ wq,
                                              const float* __restrict__ wk,
                                              const float* __restrict__ wv,
                                              const float* __restrict__ wo,
                                              const int* __restrict__ pos,
                                              u16* __restrict__ xb,
                                              u16* __restrict__ wqkvb,
                                              u16* __restrict__ wob,
                                              float* __restrict__ cs) {
  int bx = blockIdx.x, tid = threadIdx.x;
  if (bx < 8192) {
    const float* src; u16* dst; int base;
    if (bx < 4096)      { src = x;  dst = xb;                base = bx; }
    else if (bx < 5120) { src = wq; dst = wqkvb;             base = bx - 4096; }
    else if (bx < 6144) { src = wk; dst = wqkvb + (1 << 20); base = bx - 5120; }
    else if (bx < 7168) { src = wv; dst = wqkvb + (2 << 20); base = bx - 6144; }
    else                { src = wo; dst = wob;               base = bx - 7168; }
    int i4 = base * 1024 + tid * 4;
    const float4 v = *(const float4*)(src + i4);
    uint2 o;
    o.x = (unsigned)f2b(v.x) | ((unsigned)f2b(v.y) << 16);
    o.y = (unsigned)f2b(v.z) | ((unsigned)f2b(v.w) << 16);
    *(uint2*)(dst + i4) = o;
  } else {
    int idx = (bx - 8192) * 256 + tid;  // S*32 = 65536
    int i = idx & 31, s = idx >> 5;
    float p = (float)pos[s];
    float inv = expf(-(float)i * (logf(10000.0f) / 32.0f));
    float ang = p * inv;
    cs[idx * 2]     = cosf(ang);
    cs[idx * 2 + 1] = sinf(ang);
  }
}

// ---------------- gemm1 fused: C = xb @ wqkv^T, epilogue RoPE + head-major scatter ----
// K-loop LDS chunk-XOR swizzle (global addr side): slot (row,k8) holds chunk
// k8 ^ ((row>>1)&3) -> frag reads 2-way (free) instead of 8-way.
// Epilogue: Q/K paired 4-B stores (even lanes, float2 cs table); V packed
// 8-B stores using the C-layout's 4 contiguous s values per lane.
__global__ __launch_bounds__(256) void gemm_qkv(const u16* __restrict__ A,
                                                const u16* __restrict__ B,
                                                const float* __restrict__ cs,
                                                u16* __restrict__ Qr,
                                                u16* __restrict__ Kr,
                                                u16* __restrict__ VTg) {
  const int K = 1024;
  __shared__ u16 As[128 * 32];
  __shared__ u16 Bs[128 * 32];
  const int tid = threadIdx.x;
  const int wv = tid >> 6, lane = tid & 63;
  const int quad = lane >> 4, l16 = lane & 15;
  const int wm = wv & 1, wn = wv >> 1;
  const int m0 = blockIdx.y * 128, n0 = blockIdx.x * 128;
  const int kk = (quad ^ ((l16 >> 1) & 3)) * 8;  // swizzled frag chunk offset

  f32x4 acc[4][4];
  for (int i = 0; i < 4; i++)
    for (int j = 0; j < 4; j++) acc[i][j] = (f32x4){0.f, 0.f, 0.f, 0.f};

  for (int kt = 0; kt < K; kt += 32) {
    __syncthreads();
#pragma unroll
    for (int pass = 0; pass < 2; pass++) {
      int c = pass * 256 + tid;
      int row = c >> 2, k8 = (c & 3) ^ ((row >> 1) & 3);
      glds16(A + (size_t)(m0 + row) * K + kt + k8 * 8, As + (size_t)(c & ~63) * 8);
      glds16(B + (size_t)(n0 + row) * K + kt + k8 * 8, Bs + (size_t)(c & ~63) * 8);
    }
    __syncthreads();
    short8 af[4], bfr[4];
#pragma unroll
    for (int i = 0; i < 4; i++)
      af[i] = *(const short8*)(As + (wm * 64 + i * 16 + l16) * 32 + kk);
#pragma unroll
    for (int j = 0; j < 4; j++)
      bfr[j] = *(const short8*)(Bs + (wn * 64 + j * 16 + l16) * 32 + kk);
#pragma unroll
    for (int i = 0; i < 4; i++)
#pragma unroll
      for (int j = 0; j < 4; j++)
        acc[i][j] = __builtin_amdgcn_mfma_f32_16x16x32_bf16(af[i], bfr[j], acc[i][j], 0, 0, 0);
  }

  const int region = n0 >> 10;  // 0=Q 1=K 2=V (uniform per block)
  const int b = m0 >> 11;       // 128-row tile never crosses batch boundary
  if (region < 2) {
    u16* dst = region ? Kr : Qr;
    const bool evn = (l16 & 1) == 0;
    for (int i = 0; i < 4; i++)
      for (int j = 0; j < 4; j++) {
        int col = n0 + wn * 64 + j * 16 + l16;
        int cq = col & 1023;
        int h = cq >> 6, d = cq & 63, ifr = (d >> 1) & 31;
        for (int r = 0; r < 4; r++) {
          int s = (m0 & 2047) + wm * 64 + i * 16 + quad * 4 + r;
          float v = acc[i][j][r];
          float vp = __shfl_xor(v, 1);  // all lanes execute (shfl before branch)
          if (evn) {                    // v = even elem, vp = odd elem
            float2 c2 = *(const float2*)(cs + (s * 32 + ifr) * 2);
            float oe = c2.x * v - c2.y * vp;
            float oo = c2.y * v + c2.x * vp;
            unsigned pk = (unsigned)f2b(oe) | ((unsigned)f2b(oo) << 16);
            *(unsigned*)(dst + ((size_t)(b * 16 + h) * 2048 + s) * 64 + d) = pk;
          }
        }
      }
  } else {
    for (int j = 0; j < 4; j++) {
      int col = n0 + wn * 64 + j * 16 + l16;
      int cq = col & 1023;
      int h = cq >> 6, d = cq & 63;
      u16* base = VTg + ((size_t)(b * 16 + h) * 64 + d) * 2048;
      for (int i = 0; i < 4; i++) {
        int s0 = (m0 & 2047) + wm * 64 + i * 16 + quad * 4;
        uint2 o;
        o.x = (unsigned)f2b(acc[i][j][0]) | ((unsigned)f2b(acc[i][j][1]) << 16);
        o.y = (unsigned)f2b(acc[i][j][2]) | ((unsigned)f2b(acc[i][j][3]) << 16);
        *(uint2*)(base + s0) = o;  // 4 contiguous s per store
      }
    }
  }
}

// ---------------- plain bf16 GEMM, fp32 out: C[M,N] = A[M,K] @ B[N,K]^T ----------------
__global__ __launch_bounds__(256) void gemm_bt_f32(const u16* __restrict__ A,
                                                   const u16* __restrict__ B,
                                                   float* __restrict__ C,
                                                   int M, int N, int K) {
  __shared__ u16 As[128 * 32];
  __shared__ u16 Bs[128 * 32];
  const int tid = threadIdx.x;
  const int wv = tid >> 6, lane = tid & 63;
  const int quad = lane >> 4, l16 = lane & 15;
  const int wm = wv & 1, wn = wv >> 1;
  const int m0 = blockIdx.y * 128, n0 = blockIdx.x * 128;
  const int kk = (quad ^ ((l16 >> 1) & 3)) * 8;

  f32x4 acc[4][4];
  for (int i = 0; i < 4; i++)
    for (int j = 0; j < 4; j++) acc[i][j] = (f32x4){0.f, 0.f, 0.f, 0.f};

  for (int kt = 0; kt < K; kt += 32) {
    __syncthreads();
#pragma unroll
    for (int pass = 0; pass < 2; pass++) {
      int c = pass * 256 + tid;
      int row = c >> 2, k8 = (c & 3) ^ ((row >> 1) & 3);
      glds16(A + (size_t)(m0 + row) * K + kt + k8 * 8, As + (size_t)(c & ~63) * 8);
      glds16(B + (size_t)(n0 + row) * K + kt + k8 * 8, Bs + (size_t)(c & ~63) * 8);
    }
    __syncthreads();
    short8 af[4], bfr[4];
#pragma unroll
    for (int i = 0; i < 4; i++)
      af[i] = *(const short8*)(As + (wm * 64 + i * 16 + l16) * 32 + kk);
#pragma unroll
    for (int j = 0; j < 4; j++)
      bfr[j] = *(const short8*)(Bs + (wn * 64 + j * 16 + l16) * 32 + kk);
#pragma unroll
    for (int i = 0; i < 4; i++)
#pragma unroll
      for (int j = 0; j < 4; j++)
        acc[i][j] = __builtin_amdgcn_mfma_f32_16x16x32_bf16(af[i], bfr[j], acc[i][j], 0, 0, 0);
  }
  for (int i = 0; i < 4; i++)
    for (int j = 0; j < 4; j++) {
      int col = n0 + wn * 64 + j * 16 + l16;
      for (int r = 0; r < 4; r++) {
        int row = m0 + wm * 64 + i * 16 + quad * 4 + r;
        C[(size_t)row * N + col] = acc[i][j][r];
      }
    }
}

// ---------------- flash attention v4 (unchanged from round 4) ----------------
__global__ __launch_bounds__(256) void attn_k(const u16* __restrict__ Q,
                                              const u16* __restrict__ K,
                                              const u16* __restrict__ VT,
                                              float* __restrict__ Op,
                                              float* __restrict__ Lp, int S) {
  __shared__ u16 Qs[8 * 512], Ks[8 * 512], Vt[64 * 64], Ps[8 * 520];
  const int tid = threadIdx.x;
  const int wv = tid >> 6, lane = tid & 63, quad = lane >> 4, l16 = lane & 15;
  const int bh = blockIdx.y, par = blockIdx.z;
  const u16* Qg = Q + (size_t)bh * S * 64;
  const u16* Kg = K + (size_t)bh * S * 64;
  const u16* Vg = VT + (size_t)bh * S * 64;  // [64][S] per bh
  const int nqt = S >> 6;  // 32
  const float scale2 = 0.125f * 1.44269504f;  // 1/sqrt(64) * log2(e)
  const int rowbase = wv * 16 + quad * 4;
  float* Opb = Op + ((size_t)par * 32 + bh) * S * 64;
  float* Lpb = Lp + ((size_t)par * 32 + bh) * S;

  const int vrow_off = lane >> 3;
  const int vchunk = (lane & 7) ^ (lane >> 3);

  for (int t = 0; t < 2; t++) {
    const int qt = t ? (nqt - 1 - (int)blockIdx.x) : (int)blockIdx.x;
    const int q0 = qt * 64;
    for (int p = wv; p < 8; p += 4)
      glds16(Qg + (size_t)(q0 + lane) * 64 + p * 8, Qs + p * 512);
    __syncthreads();
    short8 qa0 = *(const short8*)(Qs + quad * 512 + (wv * 16 + l16) * 8);
    short8 qa1 = *(const short8*)(Qs + (4 + quad) * 512 + (wv * 16 + l16) * 8);

    f32x4 oacc[4];
    for (int j = 0; j < 4; j++) oacc[j] = (f32x4){0.f, 0.f, 0.f, 0.f};
    float l_r[4] = {0.f, 0.f, 0.f, 0.f};

    for (int kt = par; kt <= qt; kt += 2) {
      const int k0 = kt * 64;
      __syncthreads();
      for (int p = wv; p < 8; p += 4) {
        glds16(Kg + (size_t)(k0 + lane) * 64 + p * 8, Ks + p * 512);
        glds16(Vg + (size_t)(p * 8 + vrow_off) * S + k0 + vchunk * 8, Vt + p * 512);
      }
      __syncthreads();

      const bool diag = (kt == qt);
#pragma unroll
      for (int nt = 0; nt < 4; nt++) {
        f32x4 s4 = (f32x4){0.f, 0.f, 0.f, 0.f};
        short8 b0 = *(const short8*)(Ks + quad * 512 + (nt * 16 + l16) * 8);
        short8 b1 = *(const short8*)(Ks + (4 + quad) * 512 + (nt * 16 + l16) * 8);
        s4 = __builtin_amdgcn_mfma_f32_16x16x32_bf16(qa0, b0, s4, 0, 0, 0);
        s4 = __builtin_amdgcn_mfma_f32_16x16x32_bf16(qa1, b1, s4, 0, 0, 0);
        int col = nt * 16 + l16;
        int cp = col >> 3, co = col & 7;
#pragma unroll
        for (int r = 0; r < 4; r++) {
          float v = s4[r] * scale2;
          v = fminf(v, 86.f);
          if (diag && col > rowbase + r) v = -1e30f;  // exp2 -> 0
          float p = exp2f(v);
          l_r[r] += p;
          int row = rowbase + r;
          int A = (cp + 2 * (row >> 3)) & 7;
          Ps[A * 520 + row * 8 + co] = f2b_trunc(p);
        }
      }
      {
        int mr = wv * 16 + l16;
        int A0 = (quad + 2 * (mr >> 3)) & 7;
        short8 pa0 = *(const short8*)(Ps + A0 * 520 + mr * 8);
        short8 pa1 = *(const short8*)(Ps + ((A0 + 4) & 7) * 520 + mr * 8);
        int sl0 = quad ^ (l16 & 7);
#pragma unroll
        for (int nt = 0; nt < 4; nt++) {
          int d = nt * 16 + l16;
          short8 vb0 = *(const short8*)(Vt + d * 64 + sl0 * 8);
          short8 vb1 = *(const short8*)(Vt + d * 64 + (sl0 ^ 4) * 8);
          oacc[nt] = __builtin_amdgcn_mfma_f32_16x16x32_bf16(pa0, vb0, oacc[nt], 0, 0, 0);
          oacc[nt] = __builtin_amdgcn_mfma_f32_16x16x32_bf16(pa1, vb1, oacc[nt], 0, 0, 0);
        }
      }
    }
#pragma unroll
    for (int r = 0; r < 4; r++) {
      l_r[r] += __shfl_xor(l_r[r], 1);
      l_r[r] += __shfl_xor(l_r[r], 2);
      l_r[r] += __shfl_xor(l_r[r], 4);
      l_r[r] += __shfl_xor(l_r[r], 8);
    }
    if (l16 == 0)
#pragma unroll
      for (int r = 0; r < 4; r++) Lpb[q0 + rowbase + r] = l_r[r];
#pragma unroll
    for (int nt = 0; nt < 4; nt++) {
      int col = nt * 16 + l16;
#pragma unroll
      for (int r = 0; r < 4; r++)
        Opb[(size_t)(q0 + rowbase + r) * 64 + col] = oacc[nt][r];
    }
    __syncthreads();
  }
}

// ---------------- combine partials -> [B,S,H*dk] bf16 ----------------
__global__ __launch_bounds__(256) void combine_k(const float* __restrict__ Op,
                                                 const float* __restrict__ Lp,
                                                 u16* __restrict__ O, int S) {
  int idx = blockIdx.x * 256 + threadIdx.x;  // 32*2048*16 = 1M
  int d4 = idx & 15, s = (idx >> 4) & 2047, bh = idx >> 15;
  size_t po = (((size_t)bh * S) + s) * 64 + d4 * 4;
  size_t pstride = (size_t)32 * S * 64;
  float4 a = *(const float4*)(Op + po);
  float4 c = *(const float4*)(Op + pstride + po);
  float l = Lp[(size_t)bh * S + s] + Lp[(size_t)32 * S + (size_t)bh * S + s];
  float rl = 1.f / l;
  int b = bh >> 4, h = bh & 15;
  size_t oo = ((size_t)(b * S + s) * 16 + h) * 64 + d4 * 4;
  uint2 o;
  o.x = (unsigned)f2b((a.x + c.x) * rl) | ((unsigned)f2b((a.y + c.y) * rl) << 16);
  o.y = (unsigned)f2b((a.z + c.z) * rl) | ((unsigned)f2b((a.w + c.w) * rl) << 16);
  *(uint2*)(O + oo) = o;
}

extern "C" void kernel_launch(void* const* d_in, const int* in_sizes, int n_in,
                              void* d_out, int out_size, void* d_ws, size_t ws_size,
                              hipStream_t stream) {
  const float* x  = (const float*)d_in[0];
  const int*   tp = (const int*)d_in[1];
  const float* wq = (const float*)d_in[2];
  const float* wk = (const float*)d_in[3];
  const float* wvp = (const float*)d_in[4];
  const float* wo = (const float*)d_in[5];
  float* out = (float*)d_out;

  const int S = 2048, D = 1024;
  const int BS = 2 * S;  // 4096

  // workspace overlay (MB):
  //  [0,8)    xb      prep -> gemm1
  //  [8,14)   wqkvb   prep -> gemm1
  //  [14,16)  wob     prep -> gemm2
  //  [16,16.5) cs     prep -> gemm1
  //  [17,25)  qr, [25,33) kr, [33,41) vtg   gemm1 -> attn
  //  [41,41.5) lpart  attn -> combine
  //  [42,50)  ob      combine -> gemm2
  //  [50,82)  opart (2x16MB contiguous)  attn -> combine
  char* ws = (char*)d_ws;
  u16*   xb    = (u16*)(ws);
  u16*   wqkvb = (u16*)(ws + ((size_t)8 << 20));
  u16*   wob   = (u16*)(ws + ((size_t)14 << 20));
  float* cs    = (float*)(ws + ((size_t)16 << 20));
  u16*   qr    = (u16*)(ws + ((size_t)17 << 20));
  u16*   kr    = (u16*)(ws + ((size_t)25 << 20));
  u16*   vtg   = (u16*)(ws + ((size_t)33 << 20));
  float* lpart = (float*)(ws + ((size_t)41 << 20));
  u16*   ob    = (u16*)(ws + ((size_t)42 << 20));
  float* opart = (float*)(ws + ((size_t)50 << 20));

  prep_k<<<8448, 256, 0, stream>>>(x, wq, wk, wvp, wo, tp, xb, wqkvb, wob, cs);

  dim3 g1(3 * D / 128, BS / 128);
  gemm_qkv<<<g1, 256, 0, stream>>>(xb, wqkvb, cs, qr, kr, vtg);

  dim3 ga(S / 128, 32, 2);
  attn_k<<<ga, 256, 0, stream>>>(qr, kr, vtg, opart, lpart, S);

  combine_k<<<(32 * S * 16) / 256, 256, 0, stream>>>(opart, lpart, ob, S);

  dim3 g2(D / 128, BS / 128);
  gemm_bt_f32<<<g2, 256, 0, stream>>>(ob, wob, out, BS, D, D);
}

// Round 6
// 214.425 us; speedup vs baseline: 1.0983x; 1.0983x over previous
//
#include <hip/hip_runtime.h>

typedef unsigned short u16;
typedef __attribute__((ext_vector_type(8))) short short8;
typedef __attribute__((ext_vector_type(4))) float f32x4;

__device__ __forceinline__ u16 f2b(float f) {
  union { float f; unsigned u; } v; v.f = f;
  unsigned u = v.u;
  return (u16)((u + 0x7FFFu + ((u >> 16) & 1u)) >> 16);
}
__device__ __forceinline__ u16 f2b_trunc(float f) {
  union { float f; unsigned u; } v; v.f = f;
  return (u16)(v.u >> 16);
}
// async global->LDS, 16B per lane; LDS base must be wave-uniform (lane scatters +lane*16B)
__device__ __forceinline__ void glds16(const u16* g, u16* l) {
  __builtin_amdgcn_global_load_lds((const __attribute__((address_space(1))) void*)g,
                                   (__attribute__((address_space(3))) void*)l, 16, 0, 0);
}

// ---------------- fused prep: 5x fp32->bf16 convert + interleaved cos/sin table ------
__global__ __launch_bounds__(256) void prep_k(const float* __restrict__ x,
                                              const float* __restrict__ wq,
                                              const float* __restrict__ wk,
                                              const float* __restrict__ wv,
                                              const float* __restrict__ wo,
                                              const int* __restrict__ pos,
                                              u16* __restrict__ xb,
                                              u16* __restrict__ wqkvb,
                                              u16* __restrict__ wob,
                                              float* __restrict__ cs) {
  int bx = blockIdx.x, tid = threadIdx.x;
  if (bx < 8192) {
    const float* src; u16* dst; int base;
    if (bx < 4096)      { src = x;  dst = xb;                base = bx; }
    else if (bx < 5120) { src = wq; dst = wqkvb;             base = bx - 4096; }
    else if (bx < 6144) { src = wk; dst = wqkvb + (1 << 20); base = bx - 5120; }
    else if (bx < 7168) { src = wv; dst = wqkvb + (2 << 20); base = bx - 6144; }
    else                { src = wo; dst = wob;               base = bx - 7168; }
    int i4 = base * 1024 + tid * 4;
    const float4 v = *(const float4*)(src + i4);
    uint2 o;
    o.x = (unsigned)f2b(v.x) | ((unsigned)f2b(v.y) << 16);
    o.y = (unsigned)f2b(v.z) | ((unsigned)f2b(v.w) << 16);
    *(uint2*)(dst + i4) = o;
  } else {
    int idx = (bx - 8192) * 256 + tid;  // S*32 = 65536
    int i = idx & 31, s = idx >> 5;
    float p = (float)pos[s];
    float inv = expf(-(float)i * (logf(10000.0f) / 32.0f));
    float ang = p * inv;
    cs[idx * 2]     = cosf(ang);
    cs[idx * 2 + 1] = sinf(ang);
  }
}

// ---------------- gemm1 fused: C = xb @ wqkv^T, epilogue RoPE + head-major scatter ----
// 64x128 tile, BK=64, 2 waves (each 64x64 of its n-half), 16 K-iterations.
__global__ __launch_bounds__(128, 3) void gemm_qkv(const u16* __restrict__ A,
                                                   const u16* __restrict__ B,
                                                   const float* __restrict__ cs,
                                                   u16* __restrict__ Qr,
                                                   u16* __restrict__ Kr,
                                                   u16* __restrict__ VTg) {
  const int K = 1024;
  __shared__ u16 As[64 * 64];    // 8 KB
  __shared__ u16 Bs[128 * 64];   // 16 KB
  const int tid = threadIdx.x;
  const int wv = tid >> 6, lane = tid & 63;
  const int quad = lane >> 4, l16 = lane & 15;
  const int m0 = blockIdx.y * 64, n0 = blockIdx.x * 128;

  f32x4 acc[4][4];
  for (int i = 0; i < 4; i++)
    for (int j = 0; j < 4; j++) acc[i][j] = (f32x4){0.f, 0.f, 0.f, 0.f};

  for (int kt = 0; kt < K; kt += 64) {
    __syncthreads();
#pragma unroll
    for (int p = 0; p < 4; p++) {  // A: 512 chunks of 16B
      int c = p * 128 + tid;
      int row = c >> 3, k8 = c & 7;
      glds16(A + (size_t)(m0 + row) * K + kt + k8 * 8, As + (size_t)(c & ~63) * 8);
    }
#pragma unroll
    for (int p = 0; p < 8; p++) {  // B: 1024 chunks
      int c = p * 128 + tid;
      int row = c >> 3, k8 = c & 7;
      glds16(B + (size_t)(n0 + row) * K + kt + k8 * 8, Bs + (size_t)(c & ~63) * 8);
    }
    __syncthreads();
#pragma unroll
    for (int half = 0; half < 2; half++) {
      short8 af[4], bfr[4];
      const int kc = (half * 4 + quad) * 8;
#pragma unroll
      for (int i = 0; i < 4; i++)
        af[i] = *(const short8*)(As + (i * 16 + l16) * 64 + kc);
#pragma unroll
      for (int j = 0; j < 4; j++)
        bfr[j] = *(const short8*)(Bs + (wv * 64 + j * 16 + l16) * 64 + kc);
#pragma unroll
      for (int i = 0; i < 4; i++)
#pragma unroll
        for (int j = 0; j < 4; j++)
          acc[i][j] = __builtin_amdgcn_mfma_f32_16x16x32_bf16(af[i], bfr[j], acc[i][j], 0, 0, 0);
    }
  }

  const int region = n0 >> 10;  // 0=Q 1=K 2=V (uniform per block)
  const int b = m0 >> 11;       // 64-row tile never crosses batch boundary
  if (region < 2) {
    u16* dst = region ? Kr : Qr;
    const bool evn = (l16 & 1) == 0;
    for (int i = 0; i < 4; i++)
      for (int j = 0; j < 4; j++) {
        int col = n0 + wv * 64 + j * 16 + l16;
        int cq = col & 1023;
        int h = cq >> 6, d = cq & 63, ifr = (d >> 1) & 31;
        for (int r = 0; r < 4; r++) {
          int s = (m0 & 2047) + i * 16 + quad * 4 + r;
          float v = acc[i][j][r];
          float vp = __shfl_xor(v, 1);  // all lanes execute (shfl before branch)
          if (evn) {                    // v = even elem, vp = odd elem
            float2 c2 = *(const float2*)(cs + (s * 32 + ifr) * 2);
            float oe = c2.x * v - c2.y * vp;
            float oo = c2.y * v + c2.x * vp;
            unsigned pk = (unsigned)f2b(oe) | ((unsigned)f2b(oo) << 16);
            *(unsigned*)(dst + ((size_t)(b * 16 + h) * 2048 + s) * 64 + d) = pk;
          }
        }
      }
  } else {
    for (int j = 0; j < 4; j++) {
      int col = n0 + wv * 64 + j * 16 + l16;
      int cq = col & 1023;
      int h = cq >> 6, d = cq & 63;
      u16* base = VTg + ((size_t)(b * 16 + h) * 64 + d) * 2048;
      for (int i = 0; i < 4; i++) {
        int s0 = (m0 & 2047) + i * 16 + quad * 4;
        uint2 o;
        o.x = (unsigned)f2b(acc[i][j][0]) | ((unsigned)f2b(acc[i][j][1]) << 16);
        o.y = (unsigned)f2b(acc[i][j][2]) | ((unsigned)f2b(acc[i][j][3]) << 16);
        *(uint2*)(base + s0) = o;  // 4 contiguous s per store
      }
    }
  }
}

// ---------------- plain bf16 GEMM, fp32 out: 64x128 tile, BK=64, 2 waves ----------------
__global__ __launch_bounds__(128, 3) void gemm_bt_f32(const u16* __restrict__ A,
                                                      const u16* __restrict__ B,
                                                      float* __restrict__ C,
                                                      int M, int N, int K) {
  __shared__ u16 As[64 * 64];
  __shared__ u16 Bs[128 * 64];
  const int tid = threadIdx.x;
  const int wv = tid >> 6, lane = tid & 63;
  const int quad = lane >> 4, l16 = lane & 15;
  const int m0 = blockIdx.y * 64, n0 = blockIdx.x * 128;

  f32x4 acc[4][4];
  for (int i = 0; i < 4; i++)
    for (int j = 0; j < 4; j++) acc[i][j] = (f32x4){0.f, 0.f, 0.f, 0.f};

  for (int kt = 0; kt < K; kt += 64) {
    __syncthreads();
#pragma unroll
    for (int p = 0; p < 4; p++) {
      int c = p * 128 + tid;
      int row = c >> 3, k8 = c & 7;
      glds16(A + (size_t)(m0 + row) * K + kt + k8 * 8, As + (size_t)(c & ~63) * 8);
    }
#pragma unroll
    for (int p = 0; p < 8; p++) {
      int c = p * 128 + tid;
      int row = c >> 3, k8 = c & 7;
      glds16(B + (size_t)(n0 + row) * K + kt + k8 * 8, Bs + (size_t)(c & ~63) * 8);
    }
    __syncthreads();
#pragma unroll
    for (int half = 0; half < 2; half++) {
      short8 af[4], bfr[4];
      const int kc = (half * 4 + quad) * 8;
#pragma unroll
      for (int i = 0; i < 4; i++)
        af[i] = *(const short8*)(As + (i * 16 + l16) * 64 + kc);
#pragma unroll
      for (int j = 0; j < 4; j++)
        bfr[j] = *(const short8*)(Bs + (wv * 64 + j * 16 + l16) * 64 + kc);
#pragma unroll
      for (int i = 0; i < 4; i++)
#pragma unroll
        for (int j = 0; j < 4; j++)
          acc[i][j] = __builtin_amdgcn_mfma_f32_16x16x32_bf16(af[i], bfr[j], acc[i][j], 0, 0, 0);
    }
  }
  for (int i = 0; i < 4; i++)
    for (int j = 0; j < 4; j++) {
      int col = n0 + wv * 64 + j * 16 + l16;
      for (int r = 0; r < 4; r++) {
        int row = m0 + i * 16 + quad * 4 + r;
        C[(size_t)row * N + col] = acc[i][j][r];
      }
    }
}

// ---------------- flash attention v4 (unchanged) ----------------
__global__ __launch_bounds__(256) void attn_k(const u16* __restrict__ Q,
                                              const u16* __restrict__ K,
                                              const u16* __restrict__ VT,
                                              float* __restrict__ Op,
                                              float* __restrict__ Lp, int S) {
  __shared__ u16 Qs[8 * 512], Ks[8 * 512], Vt[64 * 64], Ps[8 * 520];
  const int tid = threadIdx.x;
  const int wv = tid >> 6, lane = tid & 63, quad = lane >> 4, l16 = lane & 15;
  const int bh = blockIdx.y, par = blockIdx.z;
  const u16* Qg = Q + (size_t)bh * S * 64;
  const u16* Kg = K + (size_t)bh * S * 64;
  const u16* Vg = VT + (size_t)bh * S * 64;  // [64][S] per bh
  const int nqt = S >> 6;  // 32
  const float scale2 = 0.125f * 1.44269504f;  // 1/sqrt(64) * log2(e)
  const int rowbase = wv * 16 + quad * 4;
  float* Opb = Op + ((size_t)par * 32 + bh) * S * 64;
  float* Lpb = Lp + ((size_t)par * 32 + bh) * S;

  const int vrow_off = lane >> 3;
  const int vchunk = (lane & 7) ^ (lane >> 3);

  for (int t = 0; t < 2; t++) {
    const int qt = t ? (nqt - 1 - (int)blockIdx.x) : (int)blockIdx.x;
    const int q0 = qt * 64;
    for (int p = wv; p < 8; p += 4)
      glds16(Qg + (size_t)(q0 + lane) * 64 + p * 8, Qs + p * 512);
    __syncthreads();
    short8 qa0 = *(const short8*)(Qs + quad * 512 + (wv * 16 + l16) * 8);
    short8 qa1 = *(const short8*)(Qs + (4 + quad) * 512 + (wv * 16 + l16) * 8);

    f32x4 oacc[4];
    for (int j = 0; j < 4; j++) oacc[j] = (f32x4){0.f, 0.f, 0.f, 0.f};
    float l_r[4] = {0.f, 0.f, 0.f, 0.f};

    for (int kt = par; kt <= qt; kt += 2) {
      const int k0 = kt * 64;
      __syncthreads();
      for (int p = wv; p < 8; p += 4) {
        glds16(Kg + (size_t)(k0 + lane) * 64 + p * 8, Ks + p * 512);
        glds16(Vg + (size_t)(p * 8 + vrow_off) * S + k0 + vchunk * 8, Vt + p * 512);
      }
      __syncthreads();

      const bool diag = (kt == qt);
#pragma unroll
      for (int nt = 0; nt < 4; nt++) {
        f32x4 s4 = (f32x4){0.f, 0.f, 0.f, 0.f};
        short8 b0 = *(const short8*)(Ks + quad * 512 + (nt * 16 + l16) * 8);
        short8 b1 = *(const short8*)(Ks + (4 + quad) * 512 + (nt * 16 + l16) * 8);
        s4 = __builtin_amdgcn_mfma_f32_16x16x32_bf16(qa0, b0, s4, 0, 0, 0);
        s4 = __builtin_amdgcn_mfma_f32_16x16x32_bf16(qa1, b1, s4, 0, 0, 0);
        int col = nt * 16 + l16;
        int cp = col >> 3, co = col & 7;
#pragma unroll
        for (int r = 0; r < 4; r++) {
          float v = s4[r] * scale2;
          v = fminf(v, 86.f);
          if (diag && col > rowbase + r) v = -1e30f;  // exp2 -> 0
          float p = exp2f(v);
          l_r[r] += p;
          int row = rowbase + r;
          int A = (cp + 2 * (row >> 3)) & 7;
          Ps[A * 520 + row * 8 + co] = f2b_trunc(p);
        }
      }
      {
        int mr = wv * 16 + l16;
        int A0 = (quad + 2 * (mr >> 3)) & 7;
        short8 pa0 = *(const short8*)(Ps + A0 * 520 + mr * 8);
        short8 pa1 = *(const short8*)(Ps + ((A0 + 4) & 7) * 520 + mr * 8);
        int sl0 = quad ^ (l16 & 7);
#pragma unroll
        for (int nt = 0; nt < 4; nt++) {
          int d = nt * 16 + l16;
          short8 vb0 = *(const short8*)(Vt + d * 64 + sl0 * 8);
          short8 vb1 = *(const short8*)(Vt + d * 64 + (sl0 ^ 4) * 8);
          oacc[nt] = __builtin_amdgcn_mfma_f32_16x16x32_bf16(pa0, vb0, oacc[nt], 0, 0, 0);
          oacc[nt] = __builtin_amdgcn_mfma_f32_16x16x32_bf16(pa1, vb1, oacc[nt], 0, 0, 0);
        }
      }
    }
#pragma unroll
    for (int r = 0; r < 4; r++) {
      l_r[r] += __shfl_xor(l_r[r], 1);
      l_r[r] += __shfl_xor(l_r[r], 2);
      l_r[r] += __shfl_xor(l_r[r], 4);
      l_r[r] += __shfl_xor(l_r[r], 8);
    }
    if (l16 == 0)
#pragma unroll
      for (int r = 0; r < 4; r++) Lpb[q0 + rowbase + r] = l_r[r];
#pragma unroll
    for (int nt = 0; nt < 4; nt++) {
      int col = nt * 16 + l16;
#pragma unroll
      for (int r = 0; r < 4; r++)
        Opb[(size_t)(q0 + rowbase + r) * 64 + col] = oacc[nt][r];
    }
    __syncthreads();
  }
}

// ---------------- combine partials -> [B,S,H*dk] bf16 ----------------
__global__ __launch_bounds__(256) void combine_k(const float* __restrict__ Op,
                                                 const float* __restrict__ Lp,
                                                 u16* __restrict__ O, int S) {
  int idx = blockIdx.x * 256 + threadIdx.x;  // 32*2048*16 = 1M
  int d4 = idx & 15, s = (idx >> 4) & 2047, bh = idx >> 15;
  size_t po = (((size_t)bh * S) + s) * 64 + d4 * 4;
  size_t pstride = (size_t)32 * S * 64;
  float4 a = *(const float4*)(Op + po);
  float4 c = *(const float4*)(Op + pstride + po);
  float l = Lp[(size_t)bh * S + s] + Lp[(size_t)32 * S + (size_t)bh * S + s];
  float rl = 1.f / l;
  int b = bh >> 4, h = bh & 15;
  size_t oo = ((size_t)(b * S + s) * 16 + h) * 64 + d4 * 4;
  uint2 o;
  o.x = (unsigned)f2b((a.x + c.x) * rl) | ((unsigned)f2b((a.y + c.y) * rl) << 16);
  o.y = (unsigned)f2b((a.z + c.z) * rl) | ((unsigned)f2b((a.w + c.w) * rl) << 16);
  *(uint2*)(O + oo) = o;
}

extern "C" void kernel_launch(void* const* d_in, const int* in_sizes, int n_in,
                              void* d_out, int out_size, void* d_ws, size_t ws_size,
                              hipStream_t stream) {
  const float* x  = (const float*)d_in[0];
  const int*   tp = (const int*)d_in[1];
  const float* wq = (const float*)d_in[2];
  const float* wk = (const float*)d_in[3];
  const float* wvp = (const float*)d_in[4];
  const float* wo = (const float*)d_in[5];
  float* out = (float*)d_out;

  const int S = 2048, D = 1024;
  const int BS = 2 * S;  // 4096

  // workspace overlay (MB):
  //  [0,8)    xb      prep -> gemm1
  //  [8,14)   wqkvb   prep -> gemm1
  //  [14,16)  wob     prep -> gemm2
  //  [16,16.5) cs     prep -> gemm1
  //  [17,25)  qr, [25,33) kr, [33,41) vtg   gemm1 -> attn
  //  [41,41.5) lpart  attn -> combine
  //  [42,50)  ob      combine -> gemm2
  //  [50,82)  opart (2x16MB contiguous)  attn -> combine
  char* ws = (char*)d_ws;
  u16*   xb    = (u16*)(ws);
  u16*   wqkvb = (u16*)(ws + ((size_t)8 << 20));
  u16*   wob   = (u16*)(ws + ((size_t)14 << 20));
  float* cs    = (float*)(ws + ((size_t)16 << 20));
  u16*   qr    = (u16*)(ws + ((size_t)17 << 20));
  u16*   kr    = (u16*)(ws + ((size_t)25 << 20));
  u16*   vtg   = (u16*)(ws + ((size_t)33 << 20));
  float* lpart = (float*)(ws + ((size_t)41 << 20));
  u16*   ob    = (u16*)(ws + ((size_t)42 << 20));
  float* opart = (float*)(ws + ((size_t)50 << 20));

  prep_k<<<8448, 256, 0, stream>>>(x, wq, wk, wvp, wo, tp, xb, wqkvb, wob, cs);

  dim3 g1(3 * D / 128, BS / 64);
  gemm_qkv<<<g1, 128, 0, stream>>>(xb, wqkvb, cs, qr, kr, vtg);

  dim3 ga(S / 128, 32, 2);
  attn_k<<<ga, 256, 0, stream>>>(qr, kr, vtg, opart, lpart, S);

  combine_k<<<(32 * S * 16) / 256, 256, 0, stream>>>(opart, lpart, ob, S);

  dim3 g2(D / 128, BS / 64);
  gemm_bt_f32<<<g2, 128, 0, stream>>>(ob, wob, out, BS, D, D);
}

// Round 7
// 210.453 us; speedup vs baseline: 1.1190x; 1.0189x over previous
//
#include <hip/hip_runtime.h>

typedef unsigned short u16;
typedef __attribute__((ext_vector_type(8))) short short8;
typedef __attribute__((ext_vector_type(4))) float f32x4;

__device__ __forceinline__ u16 f2b(float f) {
  union { float f; unsigned u; } v; v.f = f;
  unsigned u = v.u;
  return (u16)((u + 0x7FFFu + ((u >> 16) & 1u)) >> 16);
}
__device__ __forceinline__ u16 f2b_trunc(float f) {
  union { float f; unsigned u; } v; v.f = f;
  return (u16)(v.u >> 16);
}
// async global->LDS, 16B per lane; LDS base must be wave-uniform (lane scatters +lane*16B)
__device__ __forceinline__ void glds16(const u16* g, u16* l) {
  __builtin_amdgcn_global_load_lds((const __attribute__((address_space(1))) void*)g,
                                   (__attribute__((address_space(3))) void*)l, 16, 0, 0);
}

// ---------------- fused prep: 5x fp32->bf16 convert + interleaved cos/sin table ------
__global__ __launch_bounds__(256) void prep_k(const float* __restrict__ x,
                                              const float* __restrict__ wq,
                                              const float* __restrict__ wk,
                                              const float* __restrict__ wv,
                                              const float* __restrict__ wo,
                                              const int* __restrict__ pos,
                                              u16* __restrict__ xb,
                                              u16* __restrict__ wqkvb,
                                              u16* __restrict__ wob,
                                              float* __restrict__ cs) {
  int bx = blockIdx.x, tid = threadIdx.x;
  if (bx < 8192) {
    const float* src; u16* dst; int base;
    if (bx < 4096)      { src = x;  dst = xb;                base = bx; }
    else if (bx < 5120) { src = wq; dst = wqkvb;             base = bx - 4096; }
    else if (bx < 6144) { src = wk; dst = wqkvb + (1 << 20); base = bx - 5120; }
    else if (bx < 7168) { src = wv; dst = wqkvb + (2 << 20); base = bx - 6144; }
    else                { src = wo; dst = wob;               base = bx - 7168; }
    int i4 = base * 1024 + tid * 4;
    const float4 v = *(const float4*)(src + i4);
    uint2 o;
    o.x = (unsigned)f2b(v.x) | ((unsigned)f2b(v.y) << 16);
    o.y = (unsigned)f2b(v.z) | ((unsigned)f2b(v.w) << 16);
    *(uint2*)(dst + i4) = o;
  } else {
    int idx = (bx - 8192) * 256 + tid;  // S*32 = 65536
    int i = idx & 31, s = idx >> 5;
    float p = (float)pos[s];
    float inv = expf(-(float)i * (logf(10000.0f) / 32.0f));
    float ang = p * inv;
    cs[idx * 2]     = cosf(ang);
    cs[idx * 2 + 1] = sinf(ang);
  }
}

// ---------------- gemm1 fused: C = xb @ wqkv^T, epilogue RoPE + head-major scatter ----
// 64x128 tile, BK=64, 2 waves. Chunk-XOR swizzle: LDS slot s of row holds global
// chunk s^(row&7) -> frag-read banks span all 32 (2-way, free) vs 8-way unswizzled.
__global__ __launch_bounds__(128, 3) void gemm_qkv(const u16* __restrict__ A,
                                                   const u16* __restrict__ B,
                                                   const float* __restrict__ cs,
                                                   u16* __restrict__ Qr,
                                                   u16* __restrict__ Kr,
                                                   u16* __restrict__ VTg) {
  const int K = 1024;
  __shared__ u16 As[64 * 64];    // 8 KB
  __shared__ u16 Bs[128 * 64];   // 16 KB
  const int tid = threadIdx.x;
  const int wv = tid >> 6, lane = tid & 63;
  const int quad = lane >> 4, l16 = lane & 15;
  const int m0 = blockIdx.y * 64, n0 = blockIdx.x * 128;
  const int sw = l16 & 7;  // row&7 for all frag rows (row = i*16+l16)

  f32x4 acc[4][4];
  for (int i = 0; i < 4; i++)
    for (int j = 0; j < 4; j++) acc[i][j] = (f32x4){0.f, 0.f, 0.f, 0.f};

  for (int kt = 0; kt < K; kt += 64) {
    __syncthreads();
#pragma unroll
    for (int p = 0; p < 4; p++) {  // A: 512 chunks of 16B
      int c = p * 128 + tid;
      int row = c >> 3, k8 = (c & 7) ^ (row & 7);
      glds16(A + (size_t)(m0 + row) * K + kt + k8 * 8, As + (size_t)(c & ~63) * 8);
    }
#pragma unroll
    for (int p = 0; p < 8; p++) {  // B: 1024 chunks
      int c = p * 128 + tid;
      int row = c >> 3, k8 = (c & 7) ^ (row & 7);
      glds16(B + (size_t)(n0 + row) * K + kt + k8 * 8, Bs + (size_t)(c & ~63) * 8);
    }
    __syncthreads();
#pragma unroll
    for (int half = 0; half < 2; half++) {
      short8 af[4], bfr[4];
      const int kc = ((half * 4 + quad) ^ sw) * 8;
#pragma unroll
      for (int i = 0; i < 4; i++)
        af[i] = *(const short8*)(As + (i * 16 + l16) * 64 + kc);
#pragma unroll
      for (int j = 0; j < 4; j++)
        bfr[j] = *(const short8*)(Bs + (wv * 64 + j * 16 + l16) * 64 + kc);
#pragma unroll
      for (int i = 0; i < 4; i++)
#pragma unroll
        for (int j = 0; j < 4; j++)
          acc[i][j] = __builtin_amdgcn_mfma_f32_16x16x32_bf16(af[i], bfr[j], acc[i][j], 0, 0, 0);
    }
  }

  const int region = n0 >> 10;  // 0=Q 1=K 2=V (uniform per block)
  const int b = m0 >> 11;       // 64-row tile never crosses batch boundary
  if (region < 2) {
    u16* dst = region ? Kr : Qr;
    const bool evn = (l16 & 1) == 0;
    for (int i = 0; i < 4; i++)
      for (int j = 0; j < 4; j++) {
        int col = n0 + wv * 64 + j * 16 + l16;
        int cq = col & 1023;
        int h = cq >> 6, d = cq & 63, ifr = (d >> 1) & 31;
        for (int r = 0; r < 4; r++) {
          int s = (m0 & 2047) + i * 16 + quad * 4 + r;
          float v = acc[i][j][r];
          float vp = __shfl_xor(v, 1);  // all lanes execute (shfl before branch)
          if (evn) {                    // v = even elem, vp = odd elem
            float2 c2 = *(const float2*)(cs + (s * 32 + ifr) * 2);
            float oe = c2.x * v - c2.y * vp;
            float oo = c2.y * v + c2.x * vp;
            unsigned pk = (unsigned)f2b(oe) | ((unsigned)f2b(oo) << 16);
            *(unsigned*)(dst + ((size_t)(b * 16 + h) * 2048 + s) * 64 + d) = pk;
          }
        }
      }
  } else {
    for (int j = 0; j < 4; j++) {
      int col = n0 + wv * 64 + j * 16 + l16;
      int cq = col & 1023;
      int h = cq >> 6, d = cq & 63;
      u16* base = VTg + ((size_t)(b * 16 + h) * 64 + d) * 2048;
      for (int i = 0; i < 4; i++) {
        int s0 = (m0 & 2047) + i * 16 + quad * 4;
        uint2 o;
        o.x = (unsigned)f2b(acc[i][j][0]) | ((unsigned)f2b(acc[i][j][1]) << 16);
        o.y = (unsigned)f2b(acc[i][j][2]) | ((unsigned)f2b(acc[i][j][3]) << 16);
        *(uint2*)(base + s0) = o;  // 4 contiguous s per store
      }
    }
  }
}

// ---------------- plain bf16 GEMM, fp32 out: 64x128 tile, BK=64, swizzled ----------------
__global__ __launch_bounds__(128, 3) void gemm_bt_f32(const u16* __restrict__ A,
                                                      const u16* __restrict__ B,
                                                      float* __restrict__ C,
                                                      int M, int N, int K) {
  __shared__ u16 As[64 * 64];
  __shared__ u16 Bs[128 * 64];
  const int tid = threadIdx.x;
  const int wv = tid >> 6, lane = tid & 63;
  const int quad = lane >> 4, l16 = lane & 15;
  const int m0 = blockIdx.y * 64, n0 = blockIdx.x * 128;
  const int sw = l16 & 7;

  f32x4 acc[4][4];
  for (int i = 0; i < 4; i++)
    for (int j = 0; j < 4; j++) acc[i][j] = (f32x4){0.f, 0.f, 0.f, 0.f};

  for (int kt = 0; kt < K; kt += 64) {
    __syncthreads();
#pragma unroll
    for (int p = 0; p < 4; p++) {
      int c = p * 128 + tid;
      int row = c >> 3, k8 = (c & 7) ^ (row & 7);
      glds16(A + (size_t)(m0 + row) * K + kt + k8 * 8, As + (size_t)(c & ~63) * 8);
    }
#pragma unroll
    for (int p = 0; p < 8; p++) {
      int c = p * 128 + tid;
      int row = c >> 3, k8 = (c & 7) ^ (row & 7);
      glds16(B + (size_t)(n0 + row) * K + kt + k8 * 8, Bs + (size_t)(c & ~63) * 8);
    }
    __syncthreads();
#pragma unroll
    for (int half = 0; half < 2; half++) {
      short8 af[4], bfr[4];
      const int kc = ((half * 4 + quad) ^ sw) * 8;
#pragma unroll
      for (int i = 0; i < 4; i++)
        af[i] = *(const short8*)(As + (i * 16 + l16) * 64 + kc);
#pragma unroll
      for (int j = 0; j < 4; j++)
        bfr[j] = *(const short8*)(Bs + (wv * 64 + j * 16 + l16) * 64 + kc);
#pragma unroll
      for (int i = 0; i < 4; i++)
#pragma unroll
        for (int j = 0; j < 4; j++)
          acc[i][j] = __builtin_amdgcn_mfma_f32_16x16x32_bf16(af[i], bfr[j], acc[i][j], 0, 0, 0);
    }
  }
  for (int i = 0; i < 4; i++)
    for (int j = 0; j < 4; j++) {
      int col = n0 + wv * 64 + j * 16 + l16;
      for (int r = 0; r < 4; r++) {
        int row = m0 + i * 16 + quad * 4 + r;
        C[(size_t)row * N + col] = acc[i][j][r];
      }
    }
}

// ---------------- flash attention v5: no Q LDS (direct global frags), 6 blocks/CU ------
__global__ __launch_bounds__(256, 6) void attn_k(const u16* __restrict__ Q,
                                                 const u16* __restrict__ K,
                                                 const u16* __restrict__ VT,
                                                 float* __restrict__ Op,
                                                 float* __restrict__ Lp, int S) {
  __shared__ u16 Ks[8 * 512], Vt[64 * 64], Ps[8 * 520];  // 24.4 KB
  const int tid = threadIdx.x;
  const int wv = tid >> 6, lane = tid & 63, quad = lane >> 4, l16 = lane & 15;
  const int bh = blockIdx.y, par = blockIdx.z;
  const u16* Qg = Q + (size_t)bh * S * 64;
  const u16* Kg = K + (size_t)bh * S * 64;
  const u16* Vg = VT + (size_t)bh * S * 64;  // [64][S] per bh
  const int nqt = S >> 6;  // 32
  const float scale2 = 0.125f * 1.44269504f;  // 1/sqrt(64) * log2(e)
  const int rowbase = wv * 16 + quad * 4;
  float* Opb = Op + ((size_t)par * 32 + bh) * S * 64;
  float* Lpb = Lp + ((size_t)par * 32 + bh) * S;

  const int vrow_off = lane >> 3;
  const int vchunk = (lane & 7) ^ (lane >> 3);

  for (int t = 0; t < 2; t++) {
    const int qt = t ? (nqt - 1 - (int)blockIdx.x) : (int)blockIdx.x;
    const int q0 = qt * 64;
    // direct Q A-fragment loads (2x16B per lane, once per q-tile)
    const u16* qrow = Qg + (size_t)(q0 + wv * 16 + l16) * 64;
    short8 qa0 = *(const short8*)(qrow + quad * 8);
    short8 qa1 = *(const short8*)(qrow + 32 + quad * 8);

    f32x4 oacc[4];
    for (int j = 0; j < 4; j++) oacc[j] = (f32x4){0.f, 0.f, 0.f, 0.f};
    float l_r[4] = {0.f, 0.f, 0.f, 0.f};

    for (int kt = par; kt <= qt; kt += 2) {
      const int k0 = kt * 64;
      __syncthreads();  // prior-iter LDS consumers done
      for (int p = wv; p < 8; p += 4) {
        glds16(Kg + (size_t)(k0 + lane) * 64 + p * 8, Ks + p * 512);
        glds16(Vg + (size_t)(p * 8 + vrow_off) * S + k0 + vchunk * 8, Vt + p * 512);
      }
      __syncthreads();

      const bool diag = (kt == qt);
#pragma unroll
      for (int nt = 0; nt < 4; nt++) {
        f32x4 s4 = (f32x4){0.f, 0.f, 0.f, 0.f};
        short8 b0 = *(const short8*)(Ks + quad * 512 + (nt * 16 + l16) * 8);
        short8 b1 = *(const short8*)(Ks + (4 + quad) * 512 + (nt * 16 + l16) * 8);
        s4 = __builtin_amdgcn_mfma_f32_16x16x32_bf16(qa0, b0, s4, 0, 0, 0);
        s4 = __builtin_amdgcn_mfma_f32_16x16x32_bf16(qa1, b1, s4, 0, 0, 0);
        int col = nt * 16 + l16;
        int cp = col >> 3, co = col & 7;
#pragma unroll
        for (int r = 0; r < 4; r++) {
          float v = s4[r] * scale2;
          v = fminf(v, 86.f);
          if (diag && col > rowbase + r) v = -1e30f;  // exp2 -> 0
          float p = exp2f(v);
          l_r[r] += p;
          int row = rowbase + r;
          int A = (cp + 2 * (row >> 3)) & 7;
          Ps[A * 520 + row * 8 + co] = f2b_trunc(p);
        }
      }
      {
        int mr = wv * 16 + l16;
        int A0 = (quad + 2 * (mr >> 3)) & 7;
        short8 pa0 = *(const short8*)(Ps + A0 * 520 + mr * 8);
        short8 pa1 = *(const short8*)(Ps + ((A0 + 4) & 7) * 520 + mr * 8);
        int sl0 = quad ^ (l16 & 7);
#pragma unroll
        for (int nt = 0; nt < 4; nt++) {
          int d = nt * 16 + l16;
          short8 vb0 = *(const short8*)(Vt + d * 64 + sl0 * 8);
          short8 vb1 = *(const short8*)(Vt + d * 64 + (sl0 ^ 4) * 8);
          oacc[nt] = __builtin_amdgcn_mfma_f32_16x16x32_bf16(pa0, vb0, oacc[nt], 0, 0, 0);
          oacc[nt] = __builtin_amdgcn_mfma_f32_16x16x32_bf16(pa1, vb1, oacc[nt], 0, 0, 0);
        }
      }
    }
#pragma unroll
    for (int r = 0; r < 4; r++) {
      l_r[r] += __shfl_xor(l_r[r], 1);
      l_r[r] += __shfl_xor(l_r[r], 2);
      l_r[r] += __shfl_xor(l_r[r], 4);
      l_r[r] += __shfl_xor(l_r[r], 8);
    }
    if (l16 == 0)
#pragma unroll
      for (int r = 0; r < 4; r++) Lpb[q0 + rowbase + r] = l_r[r];
#pragma unroll
    for (int nt = 0; nt < 4; nt++) {
      int col = nt * 16 + l16;
#pragma unroll
      for (int r = 0; r < 4; r++)
        Opb[(size_t)(q0 + rowbase + r) * 64 + col] = oacc[nt][r];
    }
  }
}

// ---------------- combine partials -> [B,S,H*dk] bf16 ----------------
__global__ __launch_bounds__(256) void combine_k(const float* __restrict__ Op,
                                                 const float* __restrict__ Lp,
                                                 u16* __restrict__ O, int S) {
  int idx = blockIdx.x * 256 + threadIdx.x;  // 32*2048*16 = 1M
  int d4 = idx & 15, s = (idx >> 4) & 2047, bh = idx >> 15;
  size_t po = (((size_t)bh * S) + s) * 64 + d4 * 4;
  size_t pstride = (size_t)32 * S * 64;
  float4 a = *(const float4*)(Op + po);
  float4 c = *(const float4*)(Op + pstride + po);
  float l = Lp[(size_t)bh * S + s] + Lp[(size_t)32 * S + (size_t)bh * S + s];
  float rl = 1.f / l;
  int b = bh >> 4, h = bh & 15;
  size_t oo = ((size_t)(b * S + s) * 16 + h) * 64 + d4 * 4;
  uint2 o;
  o.x = (unsigned)f2b((a.x + c.x) * rl) | ((unsigned)f2b((a.y + c.y) * rl) << 16);
  o.y = (unsigned)f2b((a.z + c.z) * rl) | ((unsigned)f2b((a.w + c.w) * rl) << 16);
  *(uint2*)(O + oo) = o;
}

extern "C" void kernel_launch(void* const* d_in, const int* in_sizes, int n_in,
                              void* d_out, int out_size, void* d_ws, size_t ws_size,
                              hipStream_t stream) {
  const float* x  = (const float*)d_in[0];
  const int*   tp = (const int*)d_in[1];
  const float* wq = (const float*)d_in[2];
  const float* wk = (const float*)d_in[3];
  const float* wvp = (const float*)d_in[4];
  const float* wo = (const float*)d_in[5];
  float* out = (float*)d_out;

  const int S = 2048, D = 1024;
  const int BS = 2 * S;  // 4096

  // workspace overlay (MB):
  //  [0,8)    xb      prep -> gemm1
  //  [8,14)   wqkvb   prep -> gemm1
  //  [14,16)  wob     prep -> gemm2
  //  [16,16.5) cs     prep -> gemm1
  //  [17,25)  qr, [25,33) kr, [33,41) vtg   gemm1 -> attn
  //  [41,41.5) lpart  attn -> combine
  //  [42,50)  ob      combine -> gemm2
  //  [50,82)  opart (2x16MB contiguous)  attn -> combine
  char* ws = (char*)d_ws;
  u16*   xb    = (u16*)(ws);
  u16*   wqkvb = (u16*)(ws + ((size_t)8 << 20));
  u16*   wob   = (u16*)(ws + ((size_t)14 << 20));
  float* cs    = (float*)(ws + ((size_t)16 << 20));
  u16*   qr    = (u16*)(ws + ((size_t)17 << 20));
  u16*   kr    = (u16*)(ws + ((size_t)25 << 20));
  u16*   vtg   = (u16*)(ws + ((size_t)33 << 20));
  float* lpart = (float*)(ws + ((size_t)41 << 20));
  u16*   ob    = (u16*)(ws + ((size_t)42 << 20));
  float* opart = (float*)(ws + ((size_t)50 << 20));

  prep_k<<<8448, 256, 0, stream>>>(x, wq, wk, wvp, wo, tp, xb, wqkvb, wob, cs);

  dim3 g1(3 * D / 128, BS / 64);
  gemm_qkv<<<g1, 128, 0, stream>>>(xb, wqkvb, cs, qr, kr, vtg);

  dim3 ga(S / 128, 32, 2);
  attn_k<<<ga, 256, 0, stream>>>(qr, kr, vtg, opart, lpart, S);

  combine_k<<<(32 * S * 16) / 256, 256, 0, stream>>>(opart, lpart, ob, S);

  dim3 g2(D / 128, BS / 64);
  gemm_bt_f32<<<g2, 128, 0, stream>>>(ob, wob, out, BS, D, D);
}

// Round 8
// 205.084 us; speedup vs baseline: 1.1483x; 1.0262x over previous
//
#include <hip/hip_runtime.h>

typedef unsigned short u16;
typedef __attribute__((ext_vector_type(8))) short short8;
typedef __attribute__((ext_vector_type(4))) float f32x4;

__device__ __forceinline__ u16 f2b(float f) {
  union { float f; unsigned u; } v; v.f = f;
  unsigned u = v.u;
  return (u16)((u + 0x7FFFu + ((u >> 16) & 1u)) >> 16);
}
__device__ __forceinline__ u16 f2b_trunc(float f) {
  union { float f; unsigned u; } v; v.f = f;
  return (u16)(v.u >> 16);
}
// async global->LDS, 16B per lane; LDS base must be wave-uniform (lane scatters +lane*16B)
__device__ __forceinline__ void glds16(const u16* g, u16* l) {
  __builtin_amdgcn_global_load_lds((const __attribute__((address_space(1))) void*)g,
                                   (__attribute__((address_space(3))) void*)l, 16, 0, 0);
}

// ---------------- fused prep: 5x fp32->bf16 convert + interleaved cos/sin table ------
__global__ __launch_bounds__(256) void prep_k(const float* __restrict__ x,
                                              const float* __restrict__ wq,
                                              const float* __restrict__ wk,
                                              const float* __restrict__ wv,
                                              const float* __restrict__ wo,
                                              const int* __restrict__ pos,
                                              u16* __restrict__ xb,
                                              u16* __restrict__ wqkvb,
                                              u16* __restrict__ wob,
                                              float* __restrict__ cs) {
  int bx = blockIdx.x, tid = threadIdx.x;
  if (bx < 8192) {
    const float* src; u16* dst; int base;
    if (bx < 4096)      { src = x;  dst = xb;                base = bx; }
    else if (bx < 5120) { src = wq; dst = wqkvb;             base = bx - 4096; }
    else if (bx < 6144) { src = wk; dst = wqkvb + (1 << 20); base = bx - 5120; }
    else if (bx < 7168) { src = wv; dst = wqkvb + (2 << 20); base = bx - 6144; }
    else                { src = wo; dst = wob;               base = bx - 7168; }
    int i4 = base * 1024 + tid * 4;
    const float4 v = *(const float4*)(src + i4);
    uint2 o;
    o.x = (unsigned)f2b(v.x) | ((unsigned)f2b(v.y) << 16);
    o.y = (unsigned)f2b(v.z) | ((unsigned)f2b(v.w) << 16);
    *(uint2*)(dst + i4) = o;
  } else {
    int idx = (bx - 8192) * 256 + tid;  // S*32 = 65536
    int i = idx & 31, s = idx >> 5;
    float p = (float)pos[s];
    float inv = expf(-(float)i * (logf(10000.0f) / 32.0f));
    float ang = p * inv;
    cs[idx * 2]     = cosf(ang);
    cs[idx * 2 + 1] = sinf(ang);
  }
}

// ---------------- gemm1 fused: C = xb @ wqkv^T, epilogue RoPE + head-major scatter ----
// 64x128 tile, BK=64, 2 waves. Chunk-XOR swizzle: LDS slot s of row holds global
// chunk s^(row&7) -> frag-read banks span all 32 (2-way, free) vs 8-way unswizzled.
__global__ __launch_bounds__(128, 3) void gemm_qkv(const u16* __restrict__ A,
                                                   const u16* __restrict__ B,
                                                   const float* __restrict__ cs,
                                                   u16* __restrict__ Qr,
                                                   u16* __restrict__ Kr,
                                                   u16* __restrict__ VTg) {
  const int K = 1024;
  __shared__ u16 As[64 * 64];    // 8 KB
  __shared__ u16 Bs[128 * 64];   // 16 KB
  const int tid = threadIdx.x;
  const int wv = tid >> 6, lane = tid & 63;
  const int quad = lane >> 4, l16 = lane & 15;
  const int m0 = blockIdx.y * 64, n0 = blockIdx.x * 128;
  const int sw = l16 & 7;  // row&7 for all frag rows (row = i*16+l16)

  f32x4 acc[4][4];
  for (int i = 0; i < 4; i++)
    for (int j = 0; j < 4; j++) acc[i][j] = (f32x4){0.f, 0.f, 0.f, 0.f};

  for (int kt = 0; kt < K; kt += 64) {
    __syncthreads();
#pragma unroll
    for (int p = 0; p < 4; p++) {  // A: 512 chunks of 16B
      int c = p * 128 + tid;
      int row = c >> 3, k8 = (c & 7) ^ (row & 7);
      glds16(A + (size_t)(m0 + row) * K + kt + k8 * 8, As + (size_t)(c & ~63) * 8);
    }
#pragma unroll
    for (int p = 0; p < 8; p++) {  // B: 1024 chunks
      int c = p * 128 + tid;
      int row = c >> 3, k8 = (c & 7) ^ (row & 7);
      glds16(B + (size_t)(n0 + row) * K + kt + k8 * 8, Bs + (size_t)(c & ~63) * 8);
    }
    __syncthreads();
#pragma unroll
    for (int half = 0; half < 2; half++) {
      short8 af[4], bfr[4];
      const int kc = ((half * 4 + quad) ^ sw) * 8;
#pragma unroll
      for (int i = 0; i < 4; i++)
        af[i] = *(const short8*)(As + (i * 16 + l16) * 64 + kc);
#pragma unroll
      for (int j = 0; j < 4; j++)
        bfr[j] = *(const short8*)(Bs + (wv * 64 + j * 16 + l16) * 64 + kc);
#pragma unroll
      for (int i = 0; i < 4; i++)
#pragma unroll
        for (int j = 0; j < 4; j++)
          acc[i][j] = __builtin_amdgcn_mfma_f32_16x16x32_bf16(af[i], bfr[j], acc[i][j], 0, 0, 0);
    }
  }

  const int region = n0 >> 10;  // 0=Q 1=K 2=V (uniform per block)
  const int b = m0 >> 11;       // 64-row tile never crosses batch boundary
  if (region < 2) {
    u16* dst = region ? Kr : Qr;
    const bool evn = (l16 & 1) == 0;
    for (int i = 0; i < 4; i++)
      for (int j = 0; j < 4; j++) {
        int col = n0 + wv * 64 + j * 16 + l16;
        int cq = col & 1023;
        int h = cq >> 6, d = cq & 63, ifr = (d >> 1) & 31;
        for (int r = 0; r < 4; r++) {
          int s = (m0 & 2047) + i * 16 + quad * 4 + r;
          float v = acc[i][j][r];
          float vp = __shfl_xor(v, 1);  // all lanes execute (shfl before branch)
          if (evn) {                    // v = even elem, vp = odd elem
            float2 c2 = *(const float2*)(cs + (s * 32 + ifr) * 2);
            float oe = c2.x * v - c2.y * vp;
            float oo = c2.y * v + c2.x * vp;
            unsigned pk = (unsigned)f2b(oe) | ((unsigned)f2b(oo) << 16);
            *(unsigned*)(dst + ((size_t)(b * 16 + h) * 2048 + s) * 64 + d) = pk;
          }
        }
      }
  } else {
    for (int j = 0; j < 4; j++) {
      int col = n0 + wv * 64 + j * 16 + l16;
      int cq = col & 1023;
      int h = cq >> 6, d = cq & 63;
      u16* base = VTg + ((size_t)(b * 16 + h) * 64 + d) * 2048;
      for (int i = 0; i < 4; i++) {
        int s0 = (m0 & 2047) + i * 16 + quad * 4;
        uint2 o;
        o.x = (unsigned)f2b(acc[i][j][0]) | ((unsigned)f2b(acc[i][j][1]) << 16);
        o.y = (unsigned)f2b(acc[i][j][2]) | ((unsigned)f2b(acc[i][j][3]) << 16);
        *(uint2*)(base + s0) = o;  // 4 contiguous s per store
      }
    }
  }
}

// ---------------- plain bf16 GEMM, fp32 out: 64x128 tile, BK=64, swizzled ----------------
__global__ __launch_bounds__(128, 3) void gemm_bt_f32(const u16* __restrict__ A,
                                                      const u16* __restrict__ B,
                                                      float* __restrict__ C,
                                                      int M, int N, int K) {
  __shared__ u16 As[64 * 64];
  __shared__ u16 Bs[128 * 64];
  const int tid = threadIdx.x;
  const int wv = tid >> 6, lane = tid & 63;
  const int quad = lane >> 4, l16 = lane & 15;
  const int m0 = blockIdx.y * 64, n0 = blockIdx.x * 128;
  const int sw = l16 & 7;

  f32x4 acc[4][4];
  for (int i = 0; i < 4; i++)
    for (int j = 0; j < 4; j++) acc[i][j] = (f32x4){0.f, 0.f, 0.f, 0.f};

  for (int kt = 0; kt < K; kt += 64) {
    __syncthreads();
#pragma unroll
    for (int p = 0; p < 4; p++) {
      int c = p * 128 + tid;
      int row = c >> 3, k8 = (c & 7) ^ (row & 7);
      glds16(A + (size_t)(m0 + row) * K + kt + k8 * 8, As + (size_t)(c & ~63) * 8);
    }
#pragma unroll
    for (int p = 0; p < 8; p++) {
      int c = p * 128 + tid;
      int row = c >> 3, k8 = (c & 7) ^ (row & 7);
      glds16(B + (size_t)(n0 + row) * K + kt + k8 * 8, Bs + (size_t)(c & ~63) * 8);
    }
    __syncthreads();
#pragma unroll
    for (int half = 0; half < 2; half++) {
      short8 af[4], bfr[4];
      const int kc = ((half * 4 + quad) ^ sw) * 8;
#pragma unroll
      for (int i = 0; i < 4; i++)
        af[i] = *(const short8*)(As + (i * 16 + l16) * 64 + kc);
#pragma unroll
      for (int j = 0; j < 4; j++)
        bfr[j] = *(const short8*)(Bs + (wv * 64 + j * 16 + l16) * 64 + kc);
#pragma unroll
      for (int i = 0; i < 4; i++)
#pragma unroll
        for (int j = 0; j < 4; j++)
          acc[i][j] = __builtin_amdgcn_mfma_f32_16x16x32_bf16(af[i], bfr[j], acc[i][j], 0, 0, 0);
    }
  }
  for (int i = 0; i < 4; i++)
    for (int j = 0; j < 4; j++) {
      int col = n0 + wv * 64 + j * 16 + l16;
      for (int r = 0; r < 4; r++) {
        int row = m0 + i * 16 + quad * 4 + r;
        C[(size_t)row * N + col] = acc[i][j][r];
      }
    }
}

// ---------------- flash attention v6 ----------------
// No parity split, no combine: 1024 blocks (bh=32 x, slot=32 y), one 64-row
// q-tile per block, full K range, normalized bf16 output written directly.
// slot->qt map makes each CU's 4 resident blocks sum to exactly 66 iterations.
// Diag iteration specialized out of the main (unmasked) path.
__global__ __launch_bounds__(256, 6) void attn_k(const u16* __restrict__ Q,
                                                 const u16* __restrict__ K,
                                                 const u16* __restrict__ VT,
                                                 u16* __restrict__ O, int S) {
  __shared__ u16 Ks[8 * 512], Vt[64 * 64], Ps[8 * 520];  // 24.4 KB
  const int tid = threadIdx.x;
  const int wv = tid >> 6, lane = tid & 63, quad = lane >> 4, l16 = lane & 15;
  const int bh = blockIdx.x;
  const int yy = blockIdx.y, k4 = yy >> 3, g = yy & 7;
  const int qt = (k4 & 1) ? (k4 * 8 + 7 - g) : (k4 * 8 + g);  // per-CU sum-constant map
  const int q0 = qt * 64;
  const u16* Qg = Q + (size_t)bh * S * 64;
  const u16* Kg = K + (size_t)bh * S * 64;
  const u16* Vg = VT + (size_t)bh * S * 64;  // [64][S] per bh
  const float scale2 = 0.125f * 1.44269504f;  // 1/sqrt(64) * log2(e)
  const int rowbase = wv * 16 + quad * 4;

  const int vrow_off = lane >> 3;
  const int vchunk = (lane & 7) ^ (lane >> 3);

  // direct Q A-fragment loads (2x16B per lane, once per block)
  const u16* qrow = Qg + (size_t)(q0 + wv * 16 + l16) * 64;
  short8 qa0 = *(const short8*)(qrow + quad * 8);
  short8 qa1 = *(const short8*)(qrow + 32 + quad * 8);

  f32x4 oacc[4];
  for (int j = 0; j < 4; j++) oacc[j] = (f32x4){0.f, 0.f, 0.f, 0.f};
  float l_r[4] = {0.f, 0.f, 0.f, 0.f};

  for (int kt = 0; kt <= qt; kt++) {
    const int k0 = kt * 64;
    __syncthreads();  // prior-iter LDS consumers done
    for (int p = wv; p < 8; p += 4) {
      glds16(Kg + (size_t)(k0 + lane) * 64 + p * 8, Ks + p * 512);
      glds16(Vg + (size_t)(p * 8 + vrow_off) * S + k0 + vchunk * 8, Vt + p * 512);
    }
    __syncthreads();

    const bool diag = (kt == qt);  // wave-uniform
#pragma unroll
    for (int nt = 0; nt < 4; nt++) {
      f32x4 s4 = (f32x4){0.f, 0.f, 0.f, 0.f};
      short8 b0 = *(const short8*)(Ks + quad * 512 + (nt * 16 + l16) * 8);
      short8 b1 = *(const short8*)(Ks + (4 + quad) * 512 + (nt * 16 + l16) * 8);
      s4 = __builtin_amdgcn_mfma_f32_16x16x32_bf16(qa0, b0, s4, 0, 0, 0);
      s4 = __builtin_amdgcn_mfma_f32_16x16x32_bf16(qa1, b1, s4, 0, 0, 0);
      int col = nt * 16 + l16;
      int cp = col >> 3, co = col & 7;
      if (!diag) {  // main path: no mask
#pragma unroll
        for (int r = 0; r < 4; r++) {
          float v = fminf(s4[r] * scale2, 86.f);
          float p = exp2f(v);
          l_r[r] += p;
          int row = rowbase + r;
          int A = (cp + 2 * (row >> 3)) & 7;
          Ps[A * 520 + row * 8 + co] = f2b_trunc(p);
        }
      } else {      // diag tile: causal mask
#pragma unroll
        for (int r = 0; r < 4; r++) {
          float v = fminf(s4[r] * scale2, 86.f);
          if (col > rowbase + r) v = -1e30f;  // exp2 -> 0
          float p = exp2f(v);
          l_r[r] += p;
          int row = rowbase + r;
          int A = (cp + 2 * (row >> 3)) & 7;
          Ps[A * 520 + row * 8 + co] = f2b_trunc(p);
        }
      }
    }
    {
      int mr = wv * 16 + l16;
      int A0 = (quad + 2 * (mr >> 3)) & 7;
      short8 pa0 = *(const short8*)(Ps + A0 * 520 + mr * 8);
      short8 pa1 = *(const short8*)(Ps + ((A0 + 4) & 7) * 520 + mr * 8);
      int sl0 = quad ^ (l16 & 7);
#pragma unroll
      for (int nt = 0; nt < 4; nt++) {
        int d = nt * 16 + l16;
        short8 vb0 = *(const short8*)(Vt + d * 64 + sl0 * 8);
        short8 vb1 = *(const short8*)(Vt + d * 64 + (sl0 ^ 4) * 8);
        oacc[nt] = __builtin_amdgcn_mfma_f32_16x16x32_bf16(pa0, vb0, oacc[nt], 0, 0, 0);
        oacc[nt] = __builtin_amdgcn_mfma_f32_16x16x32_bf16(pa1, vb1, oacc[nt], 0, 0, 0);
      }
    }
  }
#pragma unroll
  for (int r = 0; r < 4; r++) {
    l_r[r] += __shfl_xor(l_r[r], 1);
    l_r[r] += __shfl_xor(l_r[r], 2);
    l_r[r] += __shfl_xor(l_r[r], 4);
    l_r[r] += __shfl_xor(l_r[r], 8);
    l_r[r] = 1.f / l_r[r];
  }
  // normalized bf16 output, paired-lane packed 4B stores: [B,S,H,dk]
  const int b = bh >> 4, h = bh & 15;
  const bool evn = (l16 & 1) == 0;
#pragma unroll
  for (int nt = 0; nt < 4; nt++) {
    int col = nt * 16 + l16;
#pragma unroll
    for (int r = 0; r < 4; r++) {
      float v = oacc[nt][r] * l_r[r];
      float vp = __shfl_xor(v, 1);
      if (evn) {
        int s = q0 + rowbase + r;
        unsigned pk = (unsigned)f2b(v) | ((unsigned)f2b(vp) << 16);
        *(unsigned*)(O + ((size_t)(b * S + s) * 16 + h) * 64 + col) = pk;
      }
    }
  }
}

extern "C" void kernel_launch(void* const* d_in, const int* in_sizes, int n_in,
                              void* d_out, int out_size, void* d_ws, size_t ws_size,
                              hipStream_t stream) {
  const float* x  = (const float*)d_in[0];
  const int*   tp = (const int*)d_in[1];
  const float* wq = (const float*)d_in[2];
  const float* wk = (const float*)d_in[3];
  const float* wvp = (const float*)d_in[4];
  const float* wo = (const float*)d_in[5];
  float* out = (float*)d_out;

  const int S = 2048, D = 1024;
  const int BS = 2 * S;  // 4096

  // workspace overlay (MB):
  //  [0,8)    xb      prep -> gemm1
  //  [8,14)   wqkvb   prep -> gemm1
  //  [14,16)  wob     prep -> gemm2
  //  [16,16.5) cs     prep -> gemm1
  //  [17,25)  qr, [25,33) kr, [33,41) vtg   gemm1 -> attn
  //  [42,50)  ob      attn -> gemm2
  char* ws = (char*)d_ws;
  u16*   xb    = (u16*)(ws);
  u16*   wqkvb = (u16*)(ws + ((size_t)8 << 20));
  u16*   wob   = (u16*)(ws + ((size_t)14 << 20));
  float* cs    = (float*)(ws + ((size_t)16 << 20));
  u16*   qr    = (u16*)(ws + ((size_t)17 << 20));
  u16*   kr    = (u16*)(ws + ((size_t)25 << 20));
  u16*   vtg   = (u16*)(ws + ((size_t)33 << 20));
  u16*   ob    = (u16*)(ws + ((size_t)42 << 20));

  prep_k<<<8448, 256, 0, stream>>>(x, wq, wk, wvp, wo, tp, xb, wqkvb, wob, cs);

  dim3 g1(3 * D / 128, BS / 64);
  gemm_qkv<<<g1, 128, 0, stream>>>(xb, wqkvb, cs, qr, kr, vtg);

  dim3 ga(32, 32);
  attn_k<<<ga, 256, 0, stream>>>(qr, kr, vtg, ob, S);

  dim3 g2(D / 128, BS / 64);
  gemm_bt_f32<<<g2, 128, 0, stream>>>(ob, wob, out, BS, D, D);
}

// Round 9
// 197.998 us; speedup vs baseline: 1.1894x; 1.0358x over previous
//
#include <hip/hip_runtime.h>

typedef unsigned short u16;
typedef __attribute__((ext_vector_type(8))) short short8;
typedef __attribute__((ext_vector_type(4))) float f32x4;

__device__ __forceinline__ u16 f2b(float f) {
  union { float f; unsigned u; } v; v.f = f;
  unsigned u = v.u;
  return (u16)((u + 0x7FFFu + ((u >> 16) & 1u)) >> 16);
}
__device__ __forceinline__ u16 f2b_trunc(float f) {
  union { float f; unsigned u; } v; v.f = f;
  return (u16)(v.u >> 16);
}
// async global->LDS, 16B per lane; LDS base must be wave-uniform (lane scatters +lane*16B)
__device__ __forceinline__ void glds16(const u16* g, u16* l) {
  __builtin_amdgcn_global_load_lds((const __attribute__((address_space(1))) void*)g,
                                   (__attribute__((address_space(3))) void*)l, 16, 0, 0);
}

// ---------------- fused prep: 5x fp32->bf16 convert + interleaved cos/sin table ------
__global__ __launch_bounds__(256) void prep_k(const float* __restrict__ x,
                                              const float* __restrict__ wq,
                                              const float* __restrict__ wk,
                                              const float* __restrict__ wv,
                                              const float* __restrict__ wo,
                                              const int* __restrict__ pos,
                                              u16* __restrict__ xb,
                                              u16* __restrict__ wqkvb,
                                              u16* __restrict__ wob,
                                              float* __restrict__ cs) {
  int bx = blockIdx.x, tid = threadIdx.x;
  if (bx < 8192) {
    const float* src; u16* dst; int base;
    if (bx < 4096)      { src = x;  dst = xb;                base = bx; }
    else if (bx < 5120) { src = wq; dst = wqkvb;             base = bx - 4096; }
    else if (bx < 6144) { src = wk; dst = wqkvb + (1 << 20); base = bx - 5120; }
    else if (bx < 7168) { src = wv; dst = wqkvb + (2 << 20); base = bx - 6144; }
    else                { src = wo; dst = wob;               base = bx - 7168; }
    int i4 = base * 1024 + tid * 4;
    const float4 v = *(const float4*)(src + i4);
    uint2 o;
    o.x = (unsigned)f2b(v.x) | ((unsigned)f2b(v.y) << 16);
    o.y = (unsigned)f2b(v.z) | ((unsigned)f2b(v.w) << 16);
    *(uint2*)(dst + i4) = o;
  } else {
    int idx = (bx - 8192) * 256 + tid;  // S*32 = 65536
    int i = idx & 31, s = idx >> 5;
    float p = (float)pos[s];
    float inv = expf(-(float)i * (logf(10000.0f) / 32.0f));
    float ang = p * inv;
    cs[idx * 2]     = cosf(ang);
    cs[idx * 2 + 1] = sinf(ang);
  }
}

// ---------------- gemm1 fused: C = xb @ wqkv^T, epilogue RoPE + head-major scatter ----
__global__ __launch_bounds__(128, 3) void gemm_qkv(const u16* __restrict__ A,
                                                   const u16* __restrict__ B,
                                                   const float* __restrict__ cs,
                                                   u16* __restrict__ Qr,
                                                   u16* __restrict__ Kr,
                                                   u16* __restrict__ VTg) {
  const int K = 1024;
  __shared__ u16 As[64 * 64];    // 8 KB
  __shared__ u16 Bs[128 * 64];   // 16 KB
  const int tid = threadIdx.x;
  const int wv = tid >> 6, lane = tid & 63;
  const int quad = lane >> 4, l16 = lane & 15;
  const int m0 = blockIdx.y * 64, n0 = blockIdx.x * 128;
  const int sw = l16 & 7;  // row&7 for all frag rows (row = i*16+l16)

  f32x4 acc[4][4];
  for (int i = 0; i < 4; i++)
    for (int j = 0; j < 4; j++) acc[i][j] = (f32x4){0.f, 0.f, 0.f, 0.f};

  for (int kt = 0; kt < K; kt += 64) {
    __syncthreads();
#pragma unroll
    for (int p = 0; p < 4; p++) {  // A: 512 chunks of 16B
      int c = p * 128 + tid;
      int row = c >> 3, k8 = (c & 7) ^ (row & 7);
      glds16(A + (size_t)(m0 + row) * K + kt + k8 * 8, As + (size_t)(c & ~63) * 8);
    }
#pragma unroll
    for (int p = 0; p < 8; p++) {  // B: 1024 chunks
      int c = p * 128 + tid;
      int row = c >> 3, k8 = (c & 7) ^ (row & 7);
      glds16(B + (size_t)(n0 + row) * K + kt + k8 * 8, Bs + (size_t)(c & ~63) * 8);
    }
    __syncthreads();
#pragma unroll
    for (int half = 0; half < 2; half++) {
      short8 af[4], bfr[4];
      const int kc = ((half * 4 + quad) ^ sw) * 8;
#pragma unroll
      for (int i = 0; i < 4; i++)
        af[i] = *(const short8*)(As + (i * 16 + l16) * 64 + kc);
#pragma unroll
      for (int j = 0; j < 4; j++)
        bfr[j] = *(const short8*)(Bs + (wv * 64 + j * 16 + l16) * 64 + kc);
#pragma unroll
      for (int i = 0; i < 4; i++)
#pragma unroll
        for (int j = 0; j < 4; j++)
          acc[i][j] = __builtin_amdgcn_mfma_f32_16x16x32_bf16(af[i], bfr[j], acc[i][j], 0, 0, 0);
    }
  }

  const int region = n0 >> 10;  // 0=Q 1=K 2=V (uniform per block)
  const int b = m0 >> 11;       // 64-row tile never crosses batch boundary
  if (region < 2) {
    u16* dst = region ? Kr : Qr;
    const bool evn = (l16 & 1) == 0;
    for (int i = 0; i < 4; i++)
      for (int j = 0; j < 4; j++) {
        int col = n0 + wv * 64 + j * 16 + l16;
        int cq = col & 1023;
        int h = cq >> 6, d = cq & 63, ifr = (d >> 1) & 31;
        for (int r = 0; r < 4; r++) {
          int s = (m0 & 2047) + i * 16 + quad * 4 + r;
          float v = acc[i][j][r];
          float vp = __shfl_xor(v, 1);  // all lanes execute (shfl before branch)
          if (evn) {                    // v = even elem, vp = odd elem
            float2 c2 = *(const float2*)(cs + (s * 32 + ifr) * 2);
            float oe = c2.x * v - c2.y * vp;
            float oo = c2.y * v + c2.x * vp;
            unsigned pk = (unsigned)f2b(oe) | ((unsigned)f2b(oo) << 16);
            *(unsigned*)(dst + ((size_t)(b * 16 + h) * 2048 + s) * 64 + d) = pk;
          }
        }
      }
  } else {
    for (int j = 0; j < 4; j++) {
      int col = n0 + wv * 64 + j * 16 + l16;
      int cq = col & 1023;
      int h = cq >> 6, d = cq & 63;
      u16* base = VTg + ((size_t)(b * 16 + h) * 64 + d) * 2048;
      for (int i = 0; i < 4; i++) {
        int s0 = (m0 & 2047) + i * 16 + quad * 4;
        uint2 o;
        o.x = (unsigned)f2b(acc[i][j][0]) | ((unsigned)f2b(acc[i][j][1]) << 16);
        o.y = (unsigned)f2b(acc[i][j][2]) | ((unsigned)f2b(acc[i][j][3]) << 16);
        *(uint2*)(base + s0) = o;  // 4 contiguous s per store
      }
    }
  }
}

// ---------------- plain bf16 GEMM, fp32 out: 64x128 tile, BK=64, swizzled ----------------
__global__ __launch_bounds__(128, 3) void gemm_bt_f32(const u16* __restrict__ A,
                                                      const u16* __restrict__ B,
                                                      float* __restrict__ C,
                                                      int M, int N, int K) {
  __shared__ u16 As[64 * 64];
  __shared__ u16 Bs[128 * 64];
  const int tid = threadIdx.x;
  const int wv = tid >> 6, lane = tid & 63;
  const int quad = lane >> 4, l16 = lane & 15;
  const int m0 = blockIdx.y * 64, n0 = blockIdx.x * 128;
  const int sw = l16 & 7;

  f32x4 acc[4][4];
  for (int i = 0; i < 4; i++)
    for (int j = 0; j < 4; j++) acc[i][j] = (f32x4){0.f, 0.f, 0.f, 0.f};

  for (int kt = 0; kt < K; kt += 64) {
    __syncthreads();
#pragma unroll
    for (int p = 0; p < 4; p++) {
      int c = p * 128 + tid;
      int row = c >> 3, k8 = (c & 7) ^ (row & 7);
      glds16(A + (size_t)(m0 + row) * K + kt + k8 * 8, As + (size_t)(c & ~63) * 8);
    }
#pragma unroll
    for (int p = 0; p < 8; p++) {
      int c = p * 128 + tid;
      int row = c >> 3, k8 = (c & 7) ^ (row & 7);
      glds16(B + (size_t)(n0 + row) * K + kt + k8 * 8, Bs + (size_t)(c & ~63) * 8);
    }
    __syncthreads();
#pragma unroll
    for (int half = 0; half < 2; half++) {
      short8 af[4], bfr[4];
      const int kc = ((half * 4 + quad) ^ sw) * 8;
#pragma unroll
      for (int i = 0; i < 4; i++)
        af[i] = *(const short8*)(As + (i * 16 + l16) * 64 + kc);
#pragma unroll
      for (int j = 0; j < 4; j++)
        bfr[j] = *(const short8*)(Bs + (wv * 64 + j * 16 + l16) * 64 + kc);
#pragma unroll
      for (int i = 0; i < 4; i++)
#pragma unroll
        for (int j = 0; j < 4; j++)
          acc[i][j] = __builtin_amdgcn_mfma_f32_16x16x32_bf16(af[i], bfr[j], acc[i][j], 0, 0, 0);
    }
  }
  for (int i = 0; i < 4; i++)
    for (int j = 0; j < 4; j++) {
      int col = n0 + wv * 64 + j * 16 + l16;
      for (int r = 0; r < 4; r++) {
        int row = m0 + i * 16 + quad * 4 + r;
        C[(size_t)row * N + col] = acc[i][j][r];
      }
    }
}

// ---------------- flash attention v7 ----------------
// Two q-tiles (qt=slot, 31-slot) share ONE K-sweep: K/V staged once per kt,
// tile B computed always, tile A while kt<=qtA -> uniform 33 tile-computes
// per block. Double-buffered LDS, prefetch-next-then-compute, ONE barrier per
// iteration (vmcnt drain overlaps whole compute phase). Separate PsA/PsB give
// the compiler cross-tile ILP. Grid (32 bh, 16 slots) = 512 blocks.
__global__ __launch_bounds__(256, 2) void attn_k(const u16* __restrict__ Q,
                                                 const u16* __restrict__ K,
                                                 const u16* __restrict__ VT,
                                                 u16* __restrict__ O, int S) {
  __shared__ u16 Ks[2][8 * 512], Vt[2][8 * 512];  // 16 KB + 16 KB
  __shared__ u16 PsA[8 * 520], PsB[8 * 520];      // 16.6 KB
  const int tid = threadIdx.x;
  const int wv = tid >> 6, lane = tid & 63, quad = lane >> 4, l16 = lane & 15;
  const int bh = blockIdx.x, slot = blockIdx.y;
  const int qtA = slot, qtB = 31 - slot;
  const int q0A = qtA * 64, q0B = qtB * 64;
  const u16* Qg = Q + (size_t)bh * S * 64;
  const u16* Kg = K + (size_t)bh * S * 64;
  const u16* Vg = VT + (size_t)bh * S * 64;  // [64][S] per bh
  const float scale2 = 0.125f * 1.44269504f;  // 1/sqrt(64) * log2(e)
  const int rowbase = wv * 16 + quad * 4;
  const int vrow_off = lane >> 3;
  const int vchunk = (lane & 7) ^ (lane >> 3);

  // direct Q A-fragment loads (2x16B per lane per tile)
  const u16* qrowA = Qg + (size_t)(q0A + wv * 16 + l16) * 64;
  short8 qa0A = *(const short8*)(qrowA + quad * 8);
  short8 qa1A = *(const short8*)(qrowA + 32 + quad * 8);
  const u16* qrowB = Qg + (size_t)(q0B + wv * 16 + l16) * 64;
  short8 qa0B = *(const short8*)(qrowB + quad * 8);
  short8 qa1B = *(const short8*)(qrowB + 32 + quad * 8);

  f32x4 oaccA[4], oaccB[4];
  for (int j = 0; j < 4; j++) {
    oaccA[j] = (f32x4){0.f, 0.f, 0.f, 0.f};
    oaccB[j] = (f32x4){0.f, 0.f, 0.f, 0.f};
  }
  float lA[4] = {0.f, 0.f, 0.f, 0.f}, lB[4] = {0.f, 0.f, 0.f, 0.f};

  // per-tile compute (wave-private Ps rows; no cross-wave sync needed)
  auto compute = [&](short8 qa0, short8 qa1, const u16* Ksb, const u16* Vtb,
                     u16* Psb, f32x4* oacc, float* l_r, bool diag) {
#pragma unroll
    for (int nt = 0; nt < 4; nt++) {
      f32x4 s4 = (f32x4){0.f, 0.f, 0.f, 0.f};
      short8 b0 = *(const short8*)(Ksb + quad * 512 + (nt * 16 + l16) * 8);
      short8 b1 = *(const short8*)(Ksb + (4 + quad) * 512 + (nt * 16 + l16) * 8);
      s4 = __builtin_amdgcn_mfma_f32_16x16x32_bf16(qa0, b0, s4, 0, 0, 0);
      s4 = __builtin_amdgcn_mfma_f32_16x16x32_bf16(qa1, b1, s4, 0, 0, 0);
      int col = nt * 16 + l16;
      int cp = col >> 3, co = col & 7;
#pragma unroll
      for (int r = 0; r < 4; r++) {
        float v = fminf(s4[r] * scale2, 86.f);
        if (diag && col > rowbase + r) v = -1e30f;  // exp2 -> 0
        float p = exp2f(v);
        l_r[r] += p;
        int row = rowbase + r;
        int A = (cp + 2 * (row >> 3)) & 7;
        Psb[A * 520 + row * 8 + co] = f2b_trunc(p);
      }
    }
    int mr = wv * 16 + l16;
    int A0 = (quad + 2 * (mr >> 3)) & 7;
    short8 pa0 = *(const short8*)(Psb + A0 * 520 + mr * 8);
    short8 pa1 = *(const short8*)(Psb + ((A0 + 4) & 7) * 520 + mr * 8);
    int sl0 = quad ^ (l16 & 7);
#pragma unroll
    for (int nt = 0; nt < 4; nt++) {
      int d = nt * 16 + l16;
      short8 vb0 = *(const short8*)(Vtb + d * 64 + sl0 * 8);
      short8 vb1 = *(const short8*)(Vtb + d * 64 + (sl0 ^ 4) * 8);
      oacc[nt] = __builtin_amdgcn_mfma_f32_16x16x32_bf16(pa0, vb0, oacc[nt], 0, 0, 0);
      oacc[nt] = __builtin_amdgcn_mfma_f32_16x16x32_bf16(pa1, vb1, oacc[nt], 0, 0, 0);
    }
  };

  // prologue: stage tile 0 into buffer 0
  for (int p = wv; p < 8; p += 4) {
    glds16(Kg + (size_t)(lane)*64 + p * 8, &Ks[0][p * 512]);
    glds16(Vg + (size_t)(p * 8 + vrow_off) * S + vchunk * 8, &Vt[0][p * 512]);
  }

  for (int kt = 0; kt <= qtB; kt++) {
    const int cur = kt & 1;
    __syncthreads();  // buf[cur] loads drained; prev compute on buf[cur^1] done
    if (kt < qtB) {   // prefetch next tile into the other buffer (overlaps compute)
      const int kn = (kt + 1) * 64;
      for (int p = wv; p < 8; p += 4) {
        glds16(Kg + (size_t)(kn + lane) * 64 + p * 8, &Ks[cur ^ 1][p * 512]);
        glds16(Vg + (size_t)(p * 8 + vrow_off) * S + kn + vchunk * 8, &Vt[cur ^ 1][p * 512]);
      }
    }
    compute(qa0B, qa1B, &Ks[cur][0], &Vt[cur][0], PsB, oaccB, lB, kt == qtB);
    if (kt <= qtA)
      compute(qa0A, qa1A, &Ks[cur][0], &Vt[cur][0], PsA, oaccA, lA, kt == qtA);
  }

  // epilogue: reduce l across the 16 l16 lanes, write normalized bf16 [B,S,H,dk]
  const int b = bh >> 4, h = bh & 15;
  const bool evn = (l16 & 1) == 0;
#pragma unroll
  for (int r = 0; r < 4; r++) {
    lA[r] += __shfl_xor(lA[r], 1); lA[r] += __shfl_xor(lA[r], 2);
    lA[r] += __shfl_xor(lA[r], 4); lA[r] += __shfl_xor(lA[r], 8);
    lA[r] = 1.f / lA[r];
    lB[r] += __shfl_xor(lB[r], 1); lB[r] += __shfl_xor(lB[r], 2);
    lB[r] += __shfl_xor(lB[r], 4); lB[r] += __shfl_xor(lB[r], 8);
    lB[r] = 1.f / lB[r];
  }
#pragma unroll
  for (int nt = 0; nt < 4; nt++) {
    int col = nt * 16 + l16;
#pragma unroll
    for (int r = 0; r < 4; r++) {
      float vA = oaccA[nt][r] * lA[r];
      float vAp = __shfl_xor(vA, 1);
      float vB = oaccB[nt][r] * lB[r];
      float vBp = __shfl_xor(vB, 1);
      if (evn) {
        int sA = q0A + rowbase + r;
        unsigned pkA = (unsigned)f2b(vA) | ((unsigned)f2b(vAp) << 16);
        *(unsigned*)(O + ((size_t)(b * S + sA) * 16 + h) * 64 + col) = pkA;
        int sB = q0B + rowbase + r;
        unsigned pkB = (unsigned)f2b(vB) | ((unsigned)f2b(vBp) << 16);
        *(unsigned*)(O + ((size_t)(b * S + sB) * 16 + h) * 64 + col) = pkB;
      }
    }
  }
}

extern "C" void kernel_launch(void* const* d_in, const int* in_sizes, int n_in,
                              void* d_out, int out_size, void* d_ws, size_t ws_size,
                              hipStream_t stream) {
  const float* x  = (const float*)d_in[0];
  const int*   tp = (const int*)d_in[1];
  const float* wq = (const float*)d_in[2];
  const float* wk = (const float*)d_in[3];
  const float* wvp = (const float*)d_in[4];
  const float* wo = (const float*)d_in[5];
  float* out = (float*)d_out;

  const int S = 2048, D = 1024;
  const int BS = 2 * S;  // 4096

  // workspace overlay (MB):
  //  [0,8)    xb      prep -> gemm1
  //  [8,14)   wqkvb   prep -> gemm1
  //  [14,16)  wob     prep -> gemm2
  //  [16,16.5) cs     prep -> gemm1
  //  [17,25)  qr, [25,33) kr, [33,41) vtg   gemm1 -> attn
  //  [42,50)  ob      attn -> gemm2
  char* ws = (char*)d_ws;
  u16*   xb    = (u16*)(ws);
  u16*   wqkvb = (u16*)(ws + ((size_t)8 << 20));
  u16*   wob   = (u16*)(ws + ((size_t)14 << 20));
  float* cs    = (float*)(ws + ((size_t)16 << 20));
  u16*   qr    = (u16*)(ws + ((size_t)17 << 20));
  u16*   kr    = (u16*)(ws + ((size_t)25 << 20));
  u16*   vtg   = (u16*)(ws + ((size_t)33 << 20));
  u16*   ob    = (u16*)(ws + ((size_t)42 << 20));

  prep_k<<<8448, 256, 0, stream>>>(x, wq, wk, wvp, wo, tp, xb, wqkvb, wob, cs);

  dim3 g1(3 * D / 128, BS / 64);
  gemm_qkv<<<g1, 128, 0, stream>>>(xb, wqkvb, cs, qr, kr, vtg);

  dim3 ga(32, 16);
  attn_k<<<ga, 256, 0, stream>>>(qr, kr, vtg, ob, S);

  dim3 g2(D / 128, BS / 64);
  gemm_bt_f32<<<g2, 128, 0, stream>>>(ob, wob, out, BS, D, D);
}

// Round 10
// 186.531 us; speedup vs baseline: 1.2625x; 1.0615x over previous
//
#include <hip/hip_runtime.h>

typedef unsigned short u16;
typedef __attribute__((ext_vector_type(8))) short short8;
typedef __attribute__((ext_vector_type(4))) float f32x4;

__device__ __forceinline__ u16 f2b(float f) {
  union { float f; unsigned u; } v; v.f = f;
  unsigned u = v.u;
  return (u16)((u + 0x7FFFu + ((u >> 16) & 1u)) >> 16);
}
__device__ __forceinline__ u16 f2b_trunc(float f) {
  union { float f; unsigned u; } v; v.f = f;
  return (u16)(v.u >> 16);
}
// async global->LDS, 16B per lane; LDS base must be wave-uniform (lane scatters +lane*16B)
__device__ __forceinline__ void glds16(const u16* g, u16* l) {
  __builtin_amdgcn_global_load_lds((const __attribute__((address_space(1))) void*)g,
                                   (__attribute__((address_space(3))) void*)l, 16, 0, 0);
}

// ---------------- fused prep: 5x fp32->bf16 convert + interleaved cos/sin table ------
__global__ __launch_bounds__(256) void prep_k(const float* __restrict__ x,
                                              const float* __restrict__ wq,
                                              const float* __restrict__ wk,
                                              const float* __restrict__ wv,
                                              const float* __restrict__ wo,
                                              const int* __restrict__ pos,
                                              u16* __restrict__ xb,
                                              u16* __restrict__ wqkvb,
                                              u16* __restrict__ wob,
                                              float* __restrict__ cs) {
  int bx = blockIdx.x, tid = threadIdx.x;
  if (bx < 8192) {
    const float* src; u16* dst; int base;
    if (bx < 4096)      { src = x;  dst = xb;                base = bx; }
    else if (bx < 5120) { src = wq; dst = wqkvb;             base = bx - 4096; }
    else if (bx < 6144) { src = wk; dst = wqkvb + (1 << 20); base = bx - 5120; }
    else if (bx < 7168) { src = wv; dst = wqkvb + (2 << 20); base = bx - 6144; }
    else                { src = wo; dst = wob;               base = bx - 7168; }
    int i4 = base * 1024 + tid * 4;
    const float4 v = *(const float4*)(src + i4);
    uint2 o;
    o.x = (unsigned)f2b(v.x) | ((unsigned)f2b(v.y) << 16);
    o.y = (unsigned)f2b(v.z) | ((unsigned)f2b(v.w) << 16);
    *(uint2*)(dst + i4) = o;
  } else {
    int idx = (bx - 8192) * 256 + tid;  // S*32 = 65536
    int i = idx & 31, s = idx >> 5;
    float p = (float)pos[s];
    float inv = expf(-(float)i * (logf(10000.0f) / 32.0f));
    float ang = p * inv;
    cs[idx * 2]     = cosf(ang);
    cs[idx * 2 + 1] = sinf(ang);
  }
}

// ---------------- gemm1 fused: C = xb @ wqkv^T, epilogue RoPE + head-major scatter ----
// Q outputs pre-scaled by 1/sqrt(dk)*log2(e) so attention uses raw exp2.
__global__ __launch_bounds__(128, 3) void gemm_qkv(const u16* __restrict__ A,
                                                   const u16* __restrict__ B,
                                                   const float* __restrict__ cs,
                                                   u16* __restrict__ Qr,
                                                   u16* __restrict__ Kr,
                                                   u16* __restrict__ VTg) {
  const int K = 1024;
  __shared__ u16 As[64 * 64];    // 8 KB
  __shared__ u16 Bs[128 * 64];   // 16 KB
  const int tid = threadIdx.x;
  const int wv = tid >> 6, lane = tid & 63;
  const int quad = lane >> 4, l16 = lane & 15;
  const int m0 = blockIdx.y * 64, n0 = blockIdx.x * 128;
  const int sw = l16 & 7;  // row&7 for all frag rows (row = i*16+l16)

  f32x4 acc[4][4];
  for (int i = 0; i < 4; i++)
    for (int j = 0; j < 4; j++) acc[i][j] = (f32x4){0.f, 0.f, 0.f, 0.f};

  for (int kt = 0; kt < K; kt += 64) {
    __syncthreads();
#pragma unroll
    for (int p = 0; p < 4; p++) {  // A: 512 chunks of 16B
      int c = p * 128 + tid;
      int row = c >> 3, k8 = (c & 7) ^ (row & 7);
      glds16(A + (size_t)(m0 + row) * K + kt + k8 * 8, As + (size_t)(c & ~63) * 8);
    }
#pragma unroll
    for (int p = 0; p < 8; p++) {  // B: 1024 chunks
      int c = p * 128 + tid;
      int row = c >> 3, k8 = (c & 7) ^ (row & 7);
      glds16(B + (size_t)(n0 + row) * K + kt + k8 * 8, Bs + (size_t)(c & ~63) * 8);
    }
    __syncthreads();
#pragma unroll
    for (int half = 0; half < 2; half++) {
      short8 af[4], bfr[4];
      const int kc = ((half * 4 + quad) ^ sw) * 8;
#pragma unroll
      for (int i = 0; i < 4; i++)
        af[i] = *(const short8*)(As + (i * 16 + l16) * 64 + kc);
#pragma unroll
      for (int j = 0; j < 4; j++)
        bfr[j] = *(const short8*)(Bs + (wv * 64 + j * 16 + l16) * 64 + kc);
#pragma unroll
      for (int i = 0; i < 4; i++)
#pragma unroll
        for (int j = 0; j < 4; j++)
          acc[i][j] = __builtin_amdgcn_mfma_f32_16x16x32_bf16(af[i], bfr[j], acc[i][j], 0, 0, 0);
    }
  }

  const int region = n0 >> 10;  // 0=Q 1=K 2=V (uniform per block)
  const int b = m0 >> 11;       // 64-row tile never crosses batch boundary
  if (region < 2) {
    u16* dst = region ? Kr : Qr;
    const float qs = region ? 1.0f : 0.125f * 1.44269504f;  // pre-scale Q only
    const bool evn = (l16 & 1) == 0;
    for (int i = 0; i < 4; i++)
      for (int j = 0; j < 4; j++) {
        int col = n0 + wv * 64 + j * 16 + l16;
        int cq = col & 1023;
        int h = cq >> 6, d = cq & 63, ifr = (d >> 1) & 31;
        for (int r = 0; r < 4; r++) {
          int s = (m0 & 2047) + i * 16 + quad * 4 + r;
          float v = acc[i][j][r];
          float vp = __shfl_xor(v, 1);  // all lanes execute (shfl before branch)
          if (evn) {                    // v = even elem, vp = odd elem
            float2 c2 = *(const float2*)(cs + (s * 32 + ifr) * 2);
            float oe = (c2.x * v - c2.y * vp) * qs;
            float oo = (c2.y * v + c2.x * vp) * qs;
            unsigned pk = (unsigned)f2b(oe) | ((unsigned)f2b(oo) << 16);
            *(unsigned*)(dst + ((size_t)(b * 16 + h) * 2048 + s) * 64 + d) = pk;
          }
        }
      }
  } else {
    for (int j = 0; j < 4; j++) {
      int col = n0 + wv * 64 + j * 16 + l16;
      int cq = col & 1023;
      int h = cq >> 6, d = cq & 63;
      u16* base = VTg + ((size_t)(b * 16 + h) * 64 + d) * 2048;
      for (int i = 0; i < 4; i++) {
        int s0 = (m0 & 2047) + i * 16 + quad * 4;
        uint2 o;
        o.x = (unsigned)f2b(acc[i][j][0]) | ((unsigned)f2b(acc[i][j][1]) << 16);
        o.y = (unsigned)f2b(acc[i][j][2]) | ((unsigned)f2b(acc[i][j][3]) << 16);
        *(uint2*)(base + s0) = o;  // 4 contiguous s per store
      }
    }
  }
}

// ---------------- plain bf16 GEMM, fp32 out: 64x128 tile, BK=64, swizzled ----------------
__global__ __launch_bounds__(128, 3) void gemm_bt_f32(const u16* __restrict__ A,
                                                      const u16* __restrict__ B,
                                                      float* __restrict__ C,
                                                      int M, int N, int K) {
  __shared__ u16 As[64 * 64];
  __shared__ u16 Bs[128 * 64];
  const int tid = threadIdx.x;
  const int wv = tid >> 6, lane = tid & 63;
  const int quad = lane >> 4, l16 = lane & 15;
  const int m0 = blockIdx.y * 64, n0 = blockIdx.x * 128;
  const int sw = l16 & 7;

  f32x4 acc[4][4];
  for (int i = 0; i < 4; i++)
    for (int j = 0; j < 4; j++) acc[i][j] = (f32x4){0.f, 0.f, 0.f, 0.f};

  for (int kt = 0; kt < K; kt += 64) {
    __syncthreads();
#pragma unroll
    for (int p = 0; p < 4; p++) {
      int c = p * 128 + tid;
      int row = c >> 3, k8 = (c & 7) ^ (row & 7);
      glds16(A + (size_t)(m0 + row) * K + kt + k8 * 8, As + (size_t)(c & ~63) * 8);
    }
#pragma unroll
    for (int p = 0; p < 8; p++) {
      int c = p * 128 + tid;
      int row = c >> 3, k8 = (c & 7) ^ (row & 7);
      glds16(B + (size_t)(n0 + row) * K + kt + k8 * 8, Bs + (size_t)(c & ~63) * 8);
    }
    __syncthreads();
#pragma unroll
    for (int half = 0; half < 2; half++) {
      short8 af[4], bfr[4];
      const int kc = ((half * 4 + quad) ^ sw) * 8;
#pragma unroll
      for (int i = 0; i < 4; i++)
        af[i] = *(const short8*)(As + (i * 16 + l16) * 64 + kc);
#pragma unroll
      for (int j = 0; j < 4; j++)
        bfr[j] = *(const short8*)(Bs + (wv * 64 + j * 16 + l16) * 64 + kc);
#pragma unroll
      for (int i = 0; i < 4; i++)
#pragma unroll
        for (int j = 0; j < 4; j++)
          acc[i][j] = __builtin_amdgcn_mfma_f32_16x16x32_bf16(af[i], bfr[j], acc[i][j], 0, 0, 0);
    }
  }
  for (int i = 0; i < 4; i++)
    for (int j = 0; j < 4; j++) {
      int col = n0 + wv * 64 + j * 16 + l16;
      for (int r = 0; r < 4; r++) {
        int row = m0 + i * 16 + quad * 4 + r;
        C[(size_t)row * N + col] = acc[i][j][r];
      }
    }
}

// ---------------- flash attention v8 ----------------
// 512 threads = 8 waves. Waves 0-3 own q-tile A (qt=slot), waves 4-7 tile B
// (qt=31-slot); one shared double-buffered K/V sweep (stage once, compute both).
// Each wave: ONE tile-compute per iteration (TLP instead of ILP; 16 waves/CU).
// Q pre-scaled (gemm epilogue) -> softmax is raw exp2, no mul/clamp. Diag vs
// non-diag are separate wave-uniform instantiations.
struct AttnSM {
  u16 Ks[2][8 * 512];
  u16 Vt[2][8 * 512];
  u16 Ps[2][8 * 520];
};

template <bool DIAG>
__device__ __forceinline__ void attn_tile(const u16* Ksb, const u16* Vtb, u16* Psb,
                                          short8 qa0, short8 qa1, f32x4* oacc,
                                          float* l_r, int wl, int quad, int l16) {
  const int rowbase = wl * 16 + quad * 4;
#pragma unroll
  for (int nt = 0; nt < 4; nt++) {
    f32x4 s4 = (f32x4){0.f, 0.f, 0.f, 0.f};
    short8 b0 = *(const short8*)(Ksb + quad * 512 + (nt * 16 + l16) * 8);
    short8 b1 = *(const short8*)(Ksb + (4 + quad) * 512 + (nt * 16 + l16) * 8);
    s4 = __builtin_amdgcn_mfma_f32_16x16x32_bf16(qa0, b0, s4, 0, 0, 0);
    s4 = __builtin_amdgcn_mfma_f32_16x16x32_bf16(qa1, b1, s4, 0, 0, 0);
    int col = nt * 16 + l16;
    int cp = col >> 3, co = col & 7;
#pragma unroll
    for (int r = 0; r < 4; r++) {
      float v = s4[r];
      if (DIAG && col > rowbase + r) v = -1e30f;  // exp2 -> 0
      float p = exp2f(v);
      l_r[r] += p;
      int row = rowbase + r;
      int A = (cp + 2 * (row >> 3)) & 7;
      Psb[A * 520 + row * 8 + co] = f2b_trunc(p);
    }
  }
  int mr = wl * 16 + l16;
  int A0 = (quad + 2 * (mr >> 3)) & 7;
  short8 pa0 = *(const short8*)(Psb + A0 * 520 + mr * 8);
  short8 pa1 = *(const short8*)(Psb + ((A0 + 4) & 7) * 520 + mr * 8);
  int sl0 = quad ^ (l16 & 7);
#pragma unroll
  for (int nt = 0; nt < 4; nt++) {
    int d = nt * 16 + l16;
    short8 vb0 = *(const short8*)(Vtb + d * 64 + sl0 * 8);
    short8 vb1 = *(const short8*)(Vtb + d * 64 + (sl0 ^ 4) * 8);
    oacc[nt] = __builtin_amdgcn_mfma_f32_16x16x32_bf16(pa0, vb0, oacc[nt], 0, 0, 0);
    oacc[nt] = __builtin_amdgcn_mfma_f32_16x16x32_bf16(pa1, vb1, oacc[nt], 0, 0, 0);
  }
}

__global__ __launch_bounds__(512, 4) void attn_k(const u16* __restrict__ Q,
                                                 const u16* __restrict__ K,
                                                 const u16* __restrict__ VT,
                                                 u16* __restrict__ O, int S) {
  __shared__ AttnSM sm;  // 48.25 KB
  const int tid = threadIdx.x;
  const int wv = tid >> 6, lane = tid & 63, quad = lane >> 4, l16 = lane & 15;
  const int grp = wv >> 2, wl = wv & 3;
  const int bh = blockIdx.x, slot = blockIdx.y;
  const int qtB = 31 - slot;
  const int qtMy = grp ? qtB : slot;
  const int q0My = qtMy * 64;
  const u16* Qg = Q + (size_t)bh * S * 64;
  const u16* Kg = K + (size_t)bh * S * 64;
  const u16* Vg = VT + (size_t)bh * S * 64;  // [64][S] per bh
  const int vrow_off = lane >> 3;
  const int vchunk = (lane & 7) ^ (lane >> 3);

  // direct Q A-fragment loads (Q pre-scaled by 0.125*log2e in gemm epilogue)
  const u16* qrow = Qg + (size_t)(q0My + wl * 16 + l16) * 64;
  short8 qa0 = *(const short8*)(qrow + quad * 8);
  short8 qa1 = *(const short8*)(qrow + 32 + quad * 8);

  f32x4 oacc[4];
  for (int j = 0; j < 4; j++) oacc[j] = (f32x4){0.f, 0.f, 0.f, 0.f};
  float l_r[4] = {0.f, 0.f, 0.f, 0.f};
  u16* Psb = &sm.Ps[grp][0];

  // prologue: stage tile 0 into buffer 0 (wave p stages K-plane p + V-plane p)
  glds16(Kg + (size_t)lane * 64 + wv * 8, &sm.Ks[0][wv * 512]);
  glds16(Vg + (size_t)(wv * 8 + vrow_off) * S + vchunk * 8, &sm.Vt[0][wv * 512]);

  for (int kt = 0; kt <= qtB; kt++) {
    const int cur = kt & 1;
    __syncthreads();  // buf[cur] loads drained; prev compute on buf[cur^1] done
    if (kt < qtB) {   // prefetch next tile into other buffer (overlaps compute)
      const int kn = (kt + 1) * 64;
      glds16(Kg + (size_t)(kn + lane) * 64 + wv * 8, &sm.Ks[cur ^ 1][wv * 512]);
      glds16(Vg + (size_t)(wv * 8 + vrow_off) * S + kn + vchunk * 8, &sm.Vt[cur ^ 1][wv * 512]);
    }
    if (kt < qtMy)
      attn_tile<false>(&sm.Ks[cur][0], &sm.Vt[cur][0], Psb, qa0, qa1, oacc, l_r, wl, quad, l16);
    else if (kt == qtMy)
      attn_tile<true>(&sm.Ks[cur][0], &sm.Vt[cur][0], Psb, qa0, qa1, oacc, l_r, wl, quad, l16);
  }

  // epilogue: reduce l across the 16 l16 lanes, write normalized bf16 [B,S,H,dk]
  const int b = bh >> 4, h = bh & 15;
  const bool evn = (l16 & 1) == 0;
  const int rowbase = wl * 16 + quad * 4;
#pragma unroll
  for (int r = 0; r < 4; r++) {
    l_r[r] += __shfl_xor(l_r[r], 1); l_r[r] += __shfl_xor(l_r[r], 2);
    l_r[r] += __shfl_xor(l_r[r], 4); l_r[r] += __shfl_xor(l_r[r], 8);
    l_r[r] = 1.f / l_r[r];
  }
#pragma unroll
  for (int nt = 0; nt < 4; nt++) {
    int col = nt * 16 + l16;
#pragma unroll
    for (int r = 0; r < 4; r++) {
      float v = oacc[nt][r] * l_r[r];
      float vp = __shfl_xor(v, 1);
      if (evn) {
        int s = q0My + rowbase + r;
        unsigned pk = (unsigned)f2b(v) | ((unsigned)f2b(vp) << 16);
        *(unsigned*)(O + ((size_t)(b * S + s) * 16 + h) * 64 + col) = pk;
      }
    }
  }
}

extern "C" void kernel_launch(void* const* d_in, const int* in_sizes, int n_in,
                              void* d_out, int out_size, void* d_ws, size_t ws_size,
                              hipStream_t stream) {
  const float* x  = (const float*)d_in[0];
  const int*   tp = (const int*)d_in[1];
  const float* wq = (const float*)d_in[2];
  const float* wk = (const float*)d_in[3];
  const float* wvp = (const float*)d_in[4];
  const float* wo = (const float*)d_in[5];
  float* out = (float*)d_out;

  const int S = 2048, D = 1024;
  const int BS = 2 * S;  // 4096

  // workspace overlay (MB):
  //  [0,8)    xb      prep -> gemm1
  //  [8,14)   wqkvb   prep -> gemm1
  //  [14,16)  wob     prep -> gemm2
  //  [16,16.5) cs     prep -> gemm1
  //  [17,25)  qr, [25,33) kr, [33,41) vtg   gemm1 -> attn
  //  [42,50)  ob      attn -> gemm2
  char* ws = (char*)d_ws;
  u16*   xb    = (u16*)(ws);
  u16*   wqkvb = (u16*)(ws + ((size_t)8 << 20));
  u16*   wob   = (u16*)(ws + ((size_t)14 << 20));
  float* cs    = (float*)(ws + ((size_t)16 << 20));
  u16*   qr    = (u16*)(ws + ((size_t)17 << 20));
  u16*   kr    = (u16*)(ws + ((size_t)25 << 20));
  u16*   vtg   = (u16*)(ws + ((size_t)33 << 20));
  u16*   ob    = (u16*)(ws + ((size_t)42 << 20));

  prep_k<<<8448, 256, 0, stream>>>(x, wq, wk, wvp, wo, tp, xb, wqkvb, wob, cs);

  dim3 g1(3 * D / 128, BS / 64);
  gemm_qkv<<<g1, 128, 0, stream>>>(xb, wqkvb, cs, qr, kr, vtg);

  dim3 ga(32, 16);
  attn_k<<<ga, 512, 0, stream>>>(qr, kr, vtg, ob, S);

  dim3 g2(D / 128, BS / 64);
  gemm_bt_f32<<<g2, 128, 0, stream>>>(ob, wob, out, BS, D, D);
}